// Round 1
// baseline (311.006 us; speedup 1.0000x reference)
//
#include <hip/hip_runtime.h>
#include <math.h>

#define UU 128          // coarse sample count
#define HH 32           // hidden width
#define WPB 4           // waves per block

__device__ __forceinline__ float wave_prefix_add(float v, int lane) {
  #pragma unroll
  for (int off = 1; off < 64; off <<= 1) {
    float n = __shfl_up(v, off, 64);
    if (lane >= off) v += n;
  }
  return v;
}

__device__ __forceinline__ float wave_prefix_mul(float v, int lane) {
  #pragma unroll
  for (int off = 1; off < 64; off <<= 1) {
    float n = __shfl_up(v, off, 64);
    if (lane >= off) v *= n;
  }
  return v;
}

__device__ __forceinline__ float wave_reduce_add(float v) {
  #pragma unroll
  for (int off = 32; off >= 1; off >>= 1) v += __shfl_xor(v, off, 64);
  return v;
}

// sigma = softplus(tanh(p @ W1 + b1) @ W2 + b2)
__device__ __forceinline__ float mlp_density(float px, float py, float pz,
                                             const float4* __restrict__ sWA,
                                             const float* __restrict__ sWB,
                                             float b2v) {
  float acc = b2v;
  #pragma unroll
  for (int j = 0; j < HH; ++j) {
    float4 w = sWA[j];
    float pre = fmaf(px, w.x, fmaf(py, w.y, fmaf(pz, w.z, w.w)));
    // tanh(pre), numerically stable
    float a  = fabsf(pre);
    float e  = __expf(-2.0f * a);
    float th = (1.0f - e) / (1.0f + e);
    th = (pre >= 0.0f) ? th : -th;
    acc = fmaf(th, sWB[j], acc);
  }
  // softplus(acc), numerically stable
  return fmaxf(acc, 0.0f) + log1pf(__expf(-fabsf(acc)));
}

__global__ __launch_bounds__(256) void nerf_transmittance_kernel(
    const float* __restrict__ rays_o, const float* __restrict__ rays_d,
    const float* __restrict__ nearp, const float* __restrict__ farp,
    const float* __restrict__ noise, const float* __restrict__ W1,
    const float* __restrict__ b1, const float* __restrict__ W2,
    const float* __restrict__ b2, float* __restrict__ out, int nrays) {
  __shared__ float4 sWA[HH];
  __shared__ float  sWB[HH];
  __shared__ float  szc [WPB][UU];      // coarse z (sorted)
  __shared__ float  scdf[WPB][UU];      // cdf[0..126]
  __shared__ float  snz [WPB][UU];      // importance samples (sorted)
  __shared__ float  szall[WPB][2 * UU]; // merged z

  const int tid = threadIdx.x;
  if (tid < HH) {
    sWA[tid] = make_float4(W1[tid], W1[HH + tid], W1[2 * HH + tid], b1[tid]);
    sWB[tid] = W2[tid];
  }
  __syncthreads();

  const int wave = tid >> 6;
  const int lane = tid & 63;
  const int ray  = blockIdx.x * WPB + wave;
  const bool active = ray < nrays;
  const int r = active ? ray : (nrays - 1);

  const float ox = rays_o[3 * r + 0], oy = rays_o[3 * r + 1], oz = rays_o[3 * r + 2];
  const float dx = rays_d[3 * r + 0], dy = rays_d[3 * r + 1], dz = rays_d[3 * r + 2];
  const float nv = nearp[r], fv = farp[r];
  const float b2v = b2[0];
  const float sd = (fv - nv) * (1.0f / UU);

  float* zc   = szc[wave];
  float* cdf  = scdf[wave];
  float* nz   = snz[wave];
  float* zall = szall[wave];

  // ---- coarse z (stratified jitter) ----
  float zloc[2];
  #pragma unroll
  for (int s = 0; s < 2; ++s) {
    int i = lane + 64 * s;
    float tl = (float)i * (1.0f / (UU - 1));
    float zv = fmaf(fv - nv, tl, nv) + (noise[(size_t)r * UU + i] - 0.5f) * sd;
    zloc[s] = zv;
    zc[i] = zv;
  }
  __syncthreads();

  // ---- coarse density -> alphas ----
  float alpha[2], ash[2];
  #pragma unroll
  for (int s = 0; s < 2; ++s) {
    int i = lane + 64 * s;
    float zv = zloc[s];
    float sg = mlp_density(fmaf(dx, zv, ox), fmaf(dy, zv, oy), fmaf(dz, zv, oz),
                           sWA, sWB, b2v);
    float dlt = (i < UU - 1) ? (zc[i + 1] - zv) : sd;
    float e = __expf(-dlt * sg);
    alpha[s] = 1.0f - e;
    ash[s] = e + 1e-15f;   // 1 - alpha + 1e-15
  }

  // ---- weights = alpha * exclusive cumprod(ash) over 128 samples ----
  float incl0 = wave_prefix_mul(ash[0], lane);
  float T0    = __shfl(incl0, 63, 64);
  float excl0 = __shfl_up(incl0, 1, 64);
  if (lane == 0) excl0 = 1.0f;
  float incl1 = wave_prefix_mul(ash[1], lane);
  float excl1 = __shfl_up(incl1, 1, 64);
  if (lane == 0) excl1 = 1.0f;
  excl1 *= T0;
  float w0 = alpha[0] * excl0;   // weight of sample lane
  float w1 = alpha[1] * excl1;   // weight of sample 64+lane

  // ---- pdf over samples 1..126, cdf prefix ----
  float v0 = (lane >= 1) ? (w0 + 1e-5f) : 0.0f;
  float v1 = (lane <= 62) ? (w1 + 1e-5f) : 0.0f;
  float s0   = wave_prefix_add(v0, lane);
  float tot0 = __shfl(s0, 63, 64);
  float s1   = wave_prefix_add(v1, lane) + tot0;
  float tot  = __shfl(s1, 63, 64);
  float itot = 1.0f / tot;
  cdf[lane] = s0 * itot;                      // cdf[0..63]
  if (lane <= 62) cdf[64 + lane] = s1 * itot; // cdf[64..126]
  __syncthreads();

  // ---- deterministic inverse-CDF sampling: 128 new samples ----
  #pragma unroll
  for (int s = 0; s < 2; ++s) {
    int i = lane + 64 * s;
    float u = ((float)i + 0.5f) * (1.0f / UU);
    // searchsorted(cdf[0..126], u, right)
    int lo = 0, hi = UU - 1;   // 0..127 over array of length 127
    while (lo < hi) {
      int mid = (lo + hi) >> 1;
      if (cdf[mid] <= u) lo = mid + 1; else hi = mid;
    }
    int ind = lo;                          // in [1,127]
    int below = ind - 1;
    int above = (ind < UU - 2) ? ind : (UU - 2); // min(ind,126)
    float cb = cdf[below], ca = cdf[above];
    float denom = ca - cb;
    if (denom < 1e-5f) denom = 1.0f;
    float t = (u - cb) / denom;
    float bb = 0.5f * (zc[below] + zc[below + 1]); // z_mid[below]
    float ba = 0.5f * (zc[above] + zc[above + 1]); // z_mid[above]
    nz[i] = fmaf(t, ba - bb, bb);
  }
  __syncthreads();

  // ---- merge-by-rank of sorted zc[128] and nz[128] into zall[256] ----
  #pragma unroll
  for (int s = 0; s < 2; ++s) {
    int i = lane + 64 * s;
    float a = zc[i];
    int lo = 0, hi = UU;                 // count nz[j] < a
    while (lo < hi) { int mid = (lo + hi) >> 1; if (nz[mid] < a) lo = mid + 1; else hi = mid; }
    zall[i + lo] = a;
    float bvl = nz[i];
    int lo2 = 0, hi2 = UU;               // count zc[j] <= b
    while (lo2 < hi2) { int mid = (lo2 + hi2) >> 1; if (zc[mid] <= bvl) lo2 = mid + 1; else hi2 = mid; }
    zall[i + lo2] = bvl;
  }
  __syncthreads();

  // ---- fine pass: sum sigma * delta over 256 samples ----
  float local = 0.0f;
  #pragma unroll
  for (int s = 0; s < 4; ++s) {
    int k = lane + 64 * s;
    float zv = zall[k];
    float sg = mlp_density(fmaf(dx, zv, ox), fmaf(dy, zv, oy), fmaf(dz, zv, oz),
                           sWA, sWB, b2v);
    float dlt = (k < 2 * UU - 1) ? (zall[k + 1] - zv) : sd;
    local = fmaf(sg, dlt, local);
  }
  float tsum = wave_reduce_add(local);
  if (active && lane == 0) out[ray] = __expf(-tsum);
}

extern "C" void kernel_launch(void* const* d_in, const int* in_sizes, int n_in,
                              void* d_out, int out_size, void* d_ws, size_t ws_size,
                              hipStream_t stream) {
  const float* rays_o = (const float*)d_in[0];
  const float* rays_d = (const float*)d_in[1];
  const float* nearp  = (const float*)d_in[2];
  const float* farp   = (const float*)d_in[3];
  const float* noise  = (const float*)d_in[4];
  const float* W1     = (const float*)d_in[5];
  const float* b1     = (const float*)d_in[6];
  const float* W2     = (const float*)d_in[7];
  const float* b2     = (const float*)d_in[8];
  float* out = (float*)d_out;
  const int nrays = in_sizes[2];   // near has N elements
  const int blocks = (nrays + WPB - 1) / WPB;
  nerf_transmittance_kernel<<<blocks, 256, 0, stream>>>(
      rays_o, rays_d, nearp, farp, noise, W1, b1, W2, b2, out, nrays);
}

// Round 3
// 169.513 us; speedup vs baseline: 1.8347x; 1.8347x over previous
//
#include <hip/hip_runtime.h>

#define UU 128          // coarse sample count
#define HH 32           // hidden width
#define WPB 4           // waves per block

#define LOG2E 1.44269504088896f
#define NLOG2E (-1.44269504088896f)
#define N2LOG2E (-2.88539008177793f)
#define LN2 0.693147180559945f

__device__ __forceinline__ float fast_exp2(float x) { return __builtin_amdgcn_exp2f(x); }
__device__ __forceinline__ float fast_log2(float x) { return __builtin_amdgcn_logf(x); }

__device__ __forceinline__ float wave_prefix_add(float v, int lane) {
  #pragma unroll
  for (int off = 1; off < 64; off <<= 1) {
    float n = __shfl_up(v, off, 64);
    if (lane >= off) v += n;
  }
  return v;
}

__device__ __forceinline__ float wave_prefix_mul(float v, int lane) {
  #pragma unroll
  for (int off = 1; off < 64; off <<= 1) {
    float n = __shfl_up(v, off, 64);
    if (lane >= off) v *= n;
  }
  return v;
}

__device__ __forceinline__ float wave_reduce_add(float v) {
  #pragma unroll
  for (int off = 32; off >= 1; off >>= 1) v += __shfl_xor(v, off, 64);
  return v;
}

// softplus(x) = max(x,0) + ln2 * log2(1 + 2^(-log2e*|x|))
__device__ __forceinline__ float softplus_fast(float x) {
  float e = fast_exp2(NLOG2E * __builtin_fabsf(x));
  return __builtin_fmaxf(x, 0.0f) + LN2 * fast_log2(1.0f + e);
}

// sigma for S samples at once: unit-outer loop so one LDS weight read
// serves S samples. w2r[] lives in SGPRs (uniform global loads).
template <int S>
__device__ __forceinline__ void mlp_density_multi(
    const float* px, const float* py, const float* pz,
    const float4* __restrict__ sWA, const float* __restrict__ w2r,
    float b2v, float* sg) {
  float acc[S];
  #pragma unroll
  for (int s = 0; s < S; ++s) acc[s] = b2v;
  #pragma unroll
  for (int j = 0; j < HH; ++j) {
    const float4 w = sWA[j];
    const float w2 = w2r[j];
    #pragma unroll
    for (int s = 0; s < S; ++s) {
      float pre = __builtin_fmaf(px[s], w.x, __builtin_fmaf(py[s], w.y, __builtin_fmaf(pz[s], w.z, w.w)));
      // tanh(pre) = copysign((1-e)/(1+e), pre), e = 2^(-2*log2e*|pre|)
      float e  = fast_exp2(N2LOG2E * __builtin_fabsf(pre));
      float r  = __builtin_amdgcn_rcpf(1.0f + e);
      float th = __builtin_copysignf((1.0f - e) * r, pre);
      acc[s] = __builtin_fmaf(th, w2, acc[s]);
    }
  }
  #pragma unroll
  for (int s = 0; s < S; ++s) sg[s] = softplus_fast(acc[s]);
}

__global__ __launch_bounds__(256) void nerf_transmittance_kernel(
    const float* __restrict__ rays_o, const float* __restrict__ rays_d,
    const float* __restrict__ nearp, const float* __restrict__ farp,
    const float* __restrict__ noise, const float* __restrict__ W1,
    const float* __restrict__ b1, const float* __restrict__ W2,
    const float* __restrict__ b2, float* __restrict__ out, int nrays) {
  __shared__ float4 sWA[HH];
  __shared__ float  szc [WPB][UU];      // coarse z (sorted)
  __shared__ float  scdf[WPB][UU];      // cdf[0..126]
  __shared__ float  snz [WPB][UU];      // importance samples (sorted)
  __shared__ float  szall[WPB][2 * UU]; // merged z

  const int tid = threadIdx.x;
  if (tid < HH) {
    sWA[tid] = make_float4(W1[tid], W1[HH + tid], W1[2 * HH + tid], b1[tid]);
  }

  // W2 -> SGPRs (uniform loads; v_fma takes one SGPR operand)
  float w2r[HH];
  #pragma unroll
  for (int j = 0; j < HH; ++j) w2r[j] = W2[j];
  const float b2v = b2[0];

  __syncthreads();

  const int wave = tid >> 6;
  const int lane = tid & 63;
  const int ray  = blockIdx.x * WPB + wave;
  const bool active = ray < nrays;
  const int r = active ? ray : (nrays - 1);

  const float ox = rays_o[3 * r + 0], oy = rays_o[3 * r + 1], oz = rays_o[3 * r + 2];
  const float dx = rays_d[3 * r + 0], dy = rays_d[3 * r + 1], dz = rays_d[3 * r + 2];
  const float nv = nearp[r], fv = farp[r];
  const float sd = (fv - nv) * (1.0f / UU);

  float* zc   = szc[wave];
  float* cdf  = scdf[wave];
  float* nz   = snz[wave];
  float* zall = szall[wave];

  // ---- coarse z (stratified jitter) ----
  float zloc[2];
  #pragma unroll
  for (int s = 0; s < 2; ++s) {
    int i = lane + 64 * s;
    float tl = (float)i * (1.0f / (UU - 1));
    float zv = __builtin_fmaf(fv - nv, tl, nv) + (noise[(size_t)r * UU + i] - 0.5f) * sd;
    zloc[s] = zv;
    zc[i] = zv;
  }
  __syncthreads();

  // ---- coarse density ----
  float px[4], py[4], pz[4], sg[4];
  #pragma unroll
  for (int s = 0; s < 2; ++s) {
    px[s] = __builtin_fmaf(dx, zloc[s], ox);
    py[s] = __builtin_fmaf(dy, zloc[s], oy);
    pz[s] = __builtin_fmaf(dz, zloc[s], oz);
  }
  mlp_density_multi<2>(px, py, pz, sWA, w2r, b2v, sg);

  float alpha[2], ash[2];
  #pragma unroll
  for (int s = 0; s < 2; ++s) {
    int i = lane + 64 * s;
    float dlt = (i < UU - 1) ? (zc[i + 1] - zloc[s]) : sd;
    float e = fast_exp2(NLOG2E * dlt * sg[s]);
    alpha[s] = 1.0f - e;
    ash[s] = e + 1e-15f;   // 1 - alpha + 1e-15
  }

  // ---- weights = alpha * exclusive cumprod(ash) over 128 samples ----
  float incl0 = wave_prefix_mul(ash[0], lane);
  float T0    = __shfl(incl0, 63, 64);
  float excl0 = __shfl_up(incl0, 1, 64);
  if (lane == 0) excl0 = 1.0f;
  float incl1 = wave_prefix_mul(ash[1], lane);
  float excl1 = __shfl_up(incl1, 1, 64);
  if (lane == 0) excl1 = 1.0f;
  excl1 *= T0;
  float w0 = alpha[0] * excl0;
  float w1 = alpha[1] * excl1;

  // ---- pdf over samples 1..126, cdf prefix ----
  float v0 = (lane >= 1) ? (w0 + 1e-5f) : 0.0f;
  float v1 = (lane <= 62) ? (w1 + 1e-5f) : 0.0f;
  float s0   = wave_prefix_add(v0, lane);
  float tot0 = __shfl(s0, 63, 64);
  float s1   = wave_prefix_add(v1, lane) + tot0;
  float tot  = __shfl(s1, 63, 64);
  float itot = 1.0f / tot;
  cdf[lane] = s0 * itot;
  if (lane <= 62) cdf[64 + lane] = s1 * itot;
  __syncthreads();

  // ---- deterministic inverse-CDF sampling: 128 new samples ----
  #pragma unroll
  for (int s = 0; s < 2; ++s) {
    int i = lane + 64 * s;
    float u = ((float)i + 0.5f) * (1.0f / UU);
    int lo = 0, hi = UU - 1;
    while (lo < hi) {
      int mid = (lo + hi) >> 1;
      if (cdf[mid] <= u) lo = mid + 1; else hi = mid;
    }
    int ind = lo;
    int below = ind - 1;
    int above = (ind < UU - 2) ? ind : (UU - 2);
    float cb = cdf[below], ca = cdf[above];
    float denom = ca - cb;
    if (denom < 1e-5f) denom = 1.0f;
    float t = (u - cb) * __builtin_amdgcn_rcpf(denom);
    float bb = 0.5f * (zc[below] + zc[below + 1]);
    float ba = 0.5f * (zc[above] + zc[above + 1]);
    nz[i] = __builtin_fmaf(t, ba - bb, bb);
  }
  __syncthreads();

  // ---- merge-by-rank of sorted zc[128] and nz[128] into zall[256] ----
  #pragma unroll
  for (int s = 0; s < 2; ++s) {
    int i = lane + 64 * s;
    float a = zc[i];
    int lo = 0, hi = UU;
    while (lo < hi) { int mid = (lo + hi) >> 1; if (nz[mid] < a) lo = mid + 1; else hi = mid; }
    zall[i + lo] = a;
    float bvl = nz[i];
    int lo2 = 0, hi2 = UU;
    while (lo2 < hi2) { int mid = (lo2 + hi2) >> 1; if (zc[mid] <= bvl) lo2 = mid + 1; else hi2 = mid; }
    zall[i + lo2] = bvl;
  }
  __syncthreads();

  // ---- fine pass: sum sigma * delta over 256 samples ----
  float zf[4];
  #pragma unroll
  for (int s = 0; s < 4; ++s) {
    int k = lane + 64 * s;
    zf[s] = zall[k];
    px[s] = __builtin_fmaf(dx, zf[s], ox);
    py[s] = __builtin_fmaf(dy, zf[s], oy);
    pz[s] = __builtin_fmaf(dz, zf[s], oz);
  }
  mlp_density_multi<4>(px, py, pz, sWA, w2r, b2v, sg);

  float local = 0.0f;
  #pragma unroll
  for (int s = 0; s < 4; ++s) {
    int k = lane + 64 * s;
    float dlt = (k < 2 * UU - 1) ? (zall[k + 1] - zf[s]) : sd;
    local = __builtin_fmaf(sg[s], dlt, local);
  }
  float tsum = wave_reduce_add(local);
  if (active && lane == 0) out[ray] = fast_exp2(NLOG2E * tsum);
}

extern "C" void kernel_launch(void* const* d_in, const int* in_sizes, int n_in,
                              void* d_out, int out_size, void* d_ws, size_t ws_size,
                              hipStream_t stream) {
  const float* rays_o = (const float*)d_in[0];
  const float* rays_d = (const float*)d_in[1];
  const float* nearp  = (const float*)d_in[2];
  const float* farp   = (const float*)d_in[3];
  const float* noise  = (const float*)d_in[4];
  const float* W1     = (const float*)d_in[5];
  const float* b1     = (const float*)d_in[6];
  const float* W2     = (const float*)d_in[7];
  const float* b2     = (const float*)d_in[8];
  float* out = (float*)d_out;
  const int nrays = in_sizes[2];
  const int blocks = (nrays + WPB - 1) / WPB;
  nerf_transmittance_kernel<<<blocks, 256, 0, stream>>>(
      rays_o, rays_d, nearp, farp, noise, W1, b1, W2, b2, out, nrays);
}

// Round 4
// 122.624 us; speedup vs baseline: 2.5363x; 1.3824x over previous
//
#include <hip/hip_runtime.h>

#define UU 128          // coarse sample count
#define HH 32           // hidden width
#define WPB 4           // waves per block

#define NLOG2E_F  (-1.44269504088896f)
#define TWOLOG2E_F  2.88539008177793f
#define LN2_F       0.693147180559945f

__device__ __forceinline__ float fexp2(float x){ return __builtin_amdgcn_exp2f(x); }
__device__ __forceinline__ float flog2(float x){ return __builtin_amdgcn_logf(x); }
__device__ __forceinline__ float frcp (float x){ return __builtin_amdgcn_rcpf(x); }
__device__ __forceinline__ float readlane63(float x){
  return __int_as_float(__builtin_amdgcn_readlane(__float_as_int(x), 63));
}

template<int CTRL, int RMASK>
__device__ __forceinline__ float dppmov(float x){
  return __int_as_float(__builtin_amdgcn_update_dpp(
      0, __float_as_int(x), CTRL, RMASK, 0xF, true));
}

// 64-lane inclusive add scan, classic gfx9 DPP pattern (no LDS pipe)
__device__ __forceinline__ float wscan_add(float v){
  v += dppmov<0x111, 0xF>(v);   // row_shr:1
  v += dppmov<0x112, 0xF>(v);   // row_shr:2
  v += dppmov<0x114, 0xF>(v);   // row_shr:4
  v += dppmov<0x118, 0xF>(v);   // row_shr:8
  v += dppmov<0x142, 0xA>(v);   // row_bcast:15 -> rows 1,3
  v += dppmov<0x143, 0xC>(v);   // row_bcast:31 -> rows 2,3
  return v;
}

// all LDS arrays are wave-private: drain DS queue + stop compiler reordering;
// same-wave DS ops execute in order, so no s_barrier needed.
#define LDS_FENCE() do { \
  asm volatile("s_waitcnt lgkmcnt(0)" ::: "memory"); \
  __builtin_amdgcn_wave_barrier(); \
} while (0)

// softplus(x) = max(x,0) + ln2*log2(1 + 2^(-log2e*|x|))
__device__ __forceinline__ float softplus_f(float x){
  float e = fexp2(NLOG2E_F * __builtin_fabsf(x));
  return __builtin_fmaxf(x, 0.0f) + LN2_F * flog2(1.0f + e);
}

// sigma for S samples; cg[j] = {2log2e*c_j, 2log2e*g_j} (per-ray affine fold)
template <int S>
__device__ __forceinline__ void mlp_sigma(const float* zv, const float2* cg,
                                          const float* w2r, float b2v, float* sg){
  float acc[S];
  #pragma unroll
  for (int s = 0; s < S; ++s) acc[s] = b2v;
  #pragma unroll
  for (int j = 0; j < HH; ++j) {
    const float2 c = cg[j];      // ds_read_b64 broadcast
    const float w2 = w2r[j];
    #pragma unroll
    for (int s = 0; s < S; ++s) {
      float q = __builtin_fmaf(c.y, zv[s], c.x);      // 2log2e * pre
      float e = fexp2(-__builtin_fabsf(q));            // input mods fold
      float m = (1.0f - e) * frcp(1.0f + e);           // |tanh|
      acc[s] = __builtin_fmaf(__builtin_copysignf(m, q), w2, acc[s]);
    }
  }
  #pragma unroll
  for (int s = 0; s < S; ++s) sg[s] = softplus_f(acc[s]);
}

__global__ __launch_bounds__(256) void nerf_transmittance_kernel(
    const float* __restrict__ rays_o, const float* __restrict__ rays_d,
    const float* __restrict__ nearp, const float* __restrict__ farp,
    const float* __restrict__ noise, const float* __restrict__ W1,
    const float* __restrict__ b1, const float* __restrict__ W2,
    const float* __restrict__ b2, float* __restrict__ out, int nrays) {
  __shared__ float2 scg [WPB][HH];      // per-ray {c2,g2}
  __shared__ float  szc [WPB][UU];      // coarse z (sorted)
  __shared__ float  scdf[WPB][UU];      // cdf[0..126]
  __shared__ float  snz [WPB][UU];      // importance samples (sorted)
  __shared__ float  szall[WPB][2 * UU]; // merged z

  const int tid  = threadIdx.x;
  const int wave = tid >> 6;
  const int lane = tid & 63;
  const int ray  = blockIdx.x * WPB + wave;
  const bool active = ray < nrays;
  const int r = active ? ray : (nrays - 1);

  const float ox = rays_o[3*r+0], oy = rays_o[3*r+1], oz = rays_o[3*r+2];
  const float dx = rays_d[3*r+0], dy = rays_d[3*r+1], dz = rays_d[3*r+2];
  const float nv = nearp[r], fv = farp[r];
  const float sd = (fv - nv) * (1.0f / UU);

  // W2, b2: uniform -> scalarized by compiler
  float w2r[HH];
  #pragma unroll
  for (int j = 0; j < HH; ++j) w2r[j] = W2[j];
  const float b2v = b2[0];

  float2* cg  = scg[wave];
  float* zc   = szc[wave];
  float* cdf  = scdf[wave];
  float* nz   = snz[wave];
  float* zall = szall[wave];

  // ---- per-ray affine fold: pre_j(z) = c_j + g_j*z, scaled by 2log2e ----
  if (lane < HH) {
    float wx = W1[lane], wy = W1[HH + lane], wz = W1[2*HH + lane];
    float g = dx*wx + dy*wy + dz*wz;
    float c = ox*wx + oy*wy + oz*wz + b1[lane];
    cg[lane] = make_float2(TWOLOG2E_F * c, TWOLOG2E_F * g);
  }

  // ---- coarse z (stratified jitter) ----
  float zloc[2];
  #pragma unroll
  for (int s = 0; s < 2; ++s) {
    int i = lane + 64 * s;
    float tl = (float)i * (1.0f / (UU - 1));
    float zv = __builtin_fmaf(fv - nv, tl, nv)
             + (noise[(size_t)r * UU + i] - 0.5f) * sd;
    zloc[s] = zv;
    zc[i] = zv;
  }
  LDS_FENCE();

  // ---- coarse density ----
  float sg4[4];
  mlp_sigma<2>(zloc, cg, w2r, b2v, sg4);

  // a_i = delta_i * sigma_i
  float d0 = zc[lane + 1] - zloc[0];                       // lane+1 <= 64
  float d1 = (lane < 63) ? (zc[lane + 65] - zloc[1]) : sd;
  float a0 = d0 * sg4[0];
  float a1 = d1 * sg4[1];

  // prefix sums (inclusive) of a over the 128 samples
  float S0 = wscan_add(a0);
  float S1 = wscan_add(a1) + readlane63(S0);

  // weights: w_i = T_excl - T_incl = exp2(-log2e*(S-a)) - exp2(-log2e*S)
  float w0 = fexp2(NLOG2E_F * (S0 - a0)) - fexp2(NLOG2E_F * S0);
  float w1 = fexp2(NLOG2E_F * (S1 - a1)) - fexp2(NLOG2E_F * S1);

  // ---- cdf over pdf elements 1..126 ----
  float v0 = (lane >= 1)  ? (w0 + 1e-5f) : 0.0f;
  float v1 = (lane <= 62) ? (w1 + 1e-5f) : 0.0f;
  float c0 = wscan_add(v0);
  float c1 = wscan_add(v1) + readlane63(c0);
  float tot = readlane63(c1);
  float itot = frcp(tot);
  cdf[lane] = c0 * itot;
  if (lane <= 62) cdf[64 + lane] = c1 * itot;
  LDS_FENCE();

  // ---- deterministic inverse-CDF sampling (branchless bitwise search) ----
  #pragma unroll
  for (int s = 0; s < 2; ++s) {
    int i = lane + 64 * s;
    float u = ((float)i + 0.5f) * (1.0f / UU);
    int pos = 0;                       // count of cdf[0..126] <= u  (n=127)
    #pragma unroll
    for (int bit = 64; bit >= 1; bit >>= 1) {
      float c = cdf[pos + bit - 1];    // probe <= 126
      pos += (c <= u) ? bit : 0;
    }
    int ind = pos;                     // in [1,127] since cdf[0]=0
    int below = ind - 1;
    int above = (ind < UU - 2) ? ind : (UU - 2);
    float cb = cdf[below], ca = cdf[above];
    float denom = ca - cb;
    if (denom < 1e-5f) denom = 1.0f;
    float t = (u - cb) * frcp(denom);
    float bb = 0.5f * (zc[below] + zc[below + 1]);
    float ba = 0.5f * (zc[above] + zc[above + 1]);
    nz[i] = __builtin_fmaf(t, ba - bb, bb);
  }
  LDS_FENCE();

  // ---- merge-by-rank of sorted zc[128] and nz[128] into zall[256] ----
  #pragma unroll
  for (int s = 0; s < 2; ++s) {
    int i = lane + 64 * s;
    // rank of zc[i]: count nz[j] < zc[i]
    float a = zc[i];
    int ca_ = 0;
    #pragma unroll
    for (int bit = 64; bit >= 1; bit >>= 1) {
      float vb = nz[ca_ + bit - 1];    // probes indices 0..126
      ca_ += (vb < a) ? bit : 0;
    }
    ca_ += ((ca_ == 127) && (nz[127] < a)) ? 1 : 0;
    zall[i + ca_] = a;
    // rank of nz[i]: count zc[j] <= nz[i]
    float bvl = nz[i];
    int cb_ = 0;
    #pragma unroll
    for (int bit = 64; bit >= 1; bit >>= 1) {
      float vb = zc[cb_ + bit - 1];
      cb_ += (vb <= bvl) ? bit : 0;
    }
    cb_ += ((cb_ == 127) && (zc[127] <= bvl)) ? 1 : 0;
    zall[i + cb_] = bvl;
  }
  LDS_FENCE();

  // ---- fine pass: sum sigma * delta over 256 samples ----
  float zf[4];
  #pragma unroll
  for (int s = 0; s < 4; ++s) zf[s] = zall[lane + 64 * s];
  mlp_sigma<4>(zf, cg, w2r, b2v, sg4);

  float local = 0.0f;
  #pragma unroll
  for (int s = 0; s < 4; ++s) {
    int k = lane + 64 * s;
    float dlt = (k < 2 * UU - 1) ? (zall[k + 1] - zf[s]) : sd;
    local = __builtin_fmaf(sg4[s], dlt, local);
  }
  float tsum = readlane63(wscan_add(local));
  if (active && lane == 0) out[ray] = fexp2(NLOG2E_F * tsum);
}

extern "C" void kernel_launch(void* const* d_in, const int* in_sizes, int n_in,
                              void* d_out, int out_size, void* d_ws, size_t ws_size,
                              hipStream_t stream) {
  const float* rays_o = (const float*)d_in[0];
  const float* rays_d = (const float*)d_in[1];
  const float* nearp  = (const float*)d_in[2];
  const float* farp   = (const float*)d_in[3];
  const float* noise  = (const float*)d_in[4];
  const float* W1     = (const float*)d_in[5];
  const float* b1     = (const float*)d_in[6];
  const float* W2     = (const float*)d_in[7];
  const float* b2     = (const float*)d_in[8];
  float* out = (float*)d_out;
  const int nrays = in_sizes[2];
  const int blocks = (nrays + WPB - 1) / WPB;
  nerf_transmittance_kernel<<<blocks, 256, 0, stream>>>(
      rays_o, rays_d, nearp, farp, noise, W1, b1, W2, b2, out, nrays);
}

// Round 5
// 84.905 us; speedup vs baseline: 3.6630x; 1.4442x over previous
//
#include <hip/hip_runtime.h>

#define UU 128          // coarse sample count
#define HH 32           // hidden width
#define WPB 4           // waves per block

#define NLOG2E_F  (-1.44269504088896f)
#define TWOLOG2E_F  2.88539008177793f
#define LN2_F       0.693147180559945f

__device__ __forceinline__ float fexp2(float x){ return __builtin_amdgcn_exp2f(x); }
__device__ __forceinline__ float flog2(float x){ return __builtin_amdgcn_logf(x); }
__device__ __forceinline__ float frcp (float x){ return __builtin_amdgcn_rcpf(x); }
__device__ __forceinline__ float readlane63(float x){
  return __int_as_float(__builtin_amdgcn_readlane(__float_as_int(x), 63));
}

template<int CTRL, int RMASK>
__device__ __forceinline__ float dppmov(float x){
  return __int_as_float(__builtin_amdgcn_update_dpp(
      0, __float_as_int(x), CTRL, RMASK, 0xF, true));
}

// 64-lane inclusive add scan, classic gfx9 DPP pattern (no LDS pipe)
__device__ __forceinline__ float wscan_add(float v){
  v += dppmov<0x111, 0xF>(v);   // row_shr:1
  v += dppmov<0x112, 0xF>(v);   // row_shr:2
  v += dppmov<0x114, 0xF>(v);   // row_shr:4
  v += dppmov<0x118, 0xF>(v);   // row_shr:8
  v += dppmov<0x142, 0xA>(v);   // row_bcast:15 -> rows 1,3
  v += dppmov<0x143, 0xC>(v);   // row_bcast:31 -> rows 2,3
  return v;
}

// all LDS arrays are wave-private: drain DS queue + stop compiler reordering;
// same-wave DS ops execute in order, so no s_barrier needed.
#define LDS_FENCE() do { \
  asm volatile("s_waitcnt lgkmcnt(0)" ::: "memory"); \
  __builtin_amdgcn_wave_barrier(); \
} while (0)

// softplus(x) = max(x,0) + ln2*log2(1 + 2^(-log2e*|x|))
__device__ __forceinline__ float softplus_f(float x){
  float e = fexp2(NLOG2E_F * __builtin_fabsf(x));
  return __builtin_fmaxf(x, 0.0f) + LN2_F * flog2(1.0f + e);
}

// sigma for S samples; cg[j] = {2log2e*c_j, 2log2e*g_j} (per-ray affine fold)
// tanh(x) = sign(x)*(1 - 2/(1+2^|q|)), q = 2log2e*x  (5 VALU + 2 trans)
template <int S>
__device__ __forceinline__ void mlp_sigma(const float* zv, const float2* cg,
                                          const float* w2r, float b2v, float* sg){
  float acc[S];
  #pragma unroll
  for (int s = 0; s < S; ++s) acc[s] = b2v;
  #pragma unroll
  for (int j = 0; j < HH; ++j) {
    const float2 c = cg[j];      // ds_read_b64 broadcast
    const float w2 = w2r[j];
    #pragma unroll
    for (int s = 0; s < S; ++s) {
      float q  = __builtin_fmaf(c.y, zv[s], c.x);        // 2log2e * pre
      float e2 = fexp2(__builtin_fabsf(q));               // input mod folds
      float r  = frcp(1.0f + e2);
      float m  = __builtin_fmaf(-2.0f, r, 1.0f);          // |tanh|
      acc[s] = __builtin_fmaf(__builtin_copysignf(m, q), w2, acc[s]);
    }
  }
  #pragma unroll
  for (int s = 0; s < S; ++s) sg[s] = softplus_f(acc[s]);
}

__global__ __launch_bounds__(256) void nerf_transmittance_kernel(
    const float* __restrict__ rays_o, const float* __restrict__ rays_d,
    const float* __restrict__ nearp, const float* __restrict__ farp,
    const float* __restrict__ noise, const float* __restrict__ W1,
    const float* __restrict__ b1, const float* __restrict__ W2,
    const float* __restrict__ b2, float* __restrict__ out, int nrays) {
  __shared__ float2 scg [WPB][HH];      // per-ray {c2,g2}
  __shared__ float  szc [WPB][UU];      // coarse z (sorted)
  __shared__ float  scdf[WPB][UU];      // cdf[0..126]
  __shared__ float  snz [WPB][UU];      // importance samples (sorted)
  __shared__ float  szall[WPB][2 * UU]; // merged z
  __shared__ float  sgall[WPB][2 * UU]; // merged sigma

  const int tid  = threadIdx.x;
  const int wave = tid >> 6;
  const int lane = tid & 63;
  const int ray  = blockIdx.x * WPB + wave;
  const bool active = ray < nrays;
  const int r = active ? ray : (nrays - 1);

  const float ox = rays_o[3*r+0], oy = rays_o[3*r+1], oz = rays_o[3*r+2];
  const float dx = rays_d[3*r+0], dy = rays_d[3*r+1], dz = rays_d[3*r+2];
  const float nv = nearp[r], fv = farp[r];
  const float sd = (fv - nv) * (1.0f / UU);

  // W2, b2: uniform -> scalarized by compiler (s_load)
  float w2r[HH];
  #pragma unroll
  for (int j = 0; j < HH; ++j) w2r[j] = W2[j];
  const float b2v = b2[0];

  float2* cg  = scg[wave];
  float* zc   = szc[wave];
  float* cdf  = scdf[wave];
  float* nz   = snz[wave];
  float* zall = szall[wave];
  float* gall = sgall[wave];

  // ---- per-ray affine fold: pre_j(z) = c_j + g_j*z, scaled by 2log2e ----
  if (lane < HH) {
    float wx = W1[lane], wy = W1[HH + lane], wz = W1[2*HH + lane];
    float g = dx*wx + dy*wy + dz*wz;
    float c = ox*wx + oy*wy + oz*wz + b1[lane];
    cg[lane] = make_float2(TWOLOG2E_F * c, TWOLOG2E_F * g);
  }

  // ---- coarse z (stratified jitter) ----
  float zloc[2];
  #pragma unroll
  for (int s = 0; s < 2; ++s) {
    int i = lane + 64 * s;
    float tl = (float)i * (1.0f / (UU - 1));
    float zv = __builtin_fmaf(fv - nv, tl, nv)
             + (noise[(size_t)r * UU + i] - 0.5f) * sd;
    zloc[s] = zv;
    zc[i] = zv;
  }
  LDS_FENCE();

  // ---- coarse density (kept for reuse in the fine pass) ----
  float sgc[2];
  mlp_sigma<2>(zloc, cg, w2r, b2v, sgc);

  // a_i = delta_i * sigma_i
  float d0 = zc[lane + 1] - zloc[0];                       // lane+1 <= 64
  float d1 = (lane < 63) ? (zc[lane + 65] - zloc[1]) : sd;
  float a0 = d0 * sgc[0];
  float a1 = d1 * sgc[1];

  // prefix sums (inclusive) of a over the 128 samples
  float S0 = wscan_add(a0);
  float S1 = wscan_add(a1) + readlane63(S0);

  // weights: w_i = T_excl - T_incl = exp2(-log2e*(S-a)) - exp2(-log2e*S)
  float w0 = fexp2(NLOG2E_F * (S0 - a0)) - fexp2(NLOG2E_F * S0);
  float w1 = fexp2(NLOG2E_F * (S1 - a1)) - fexp2(NLOG2E_F * S1);

  // ---- cdf over pdf elements 1..126 ----
  float v0 = (lane >= 1)  ? (w0 + 1e-5f) : 0.0f;
  float v1 = (lane <= 62) ? (w1 + 1e-5f) : 0.0f;
  float c0 = wscan_add(v0);
  float c1 = wscan_add(v1) + readlane63(c0);
  float tot = readlane63(c1);
  float itot = frcp(tot);
  cdf[lane] = c0 * itot;
  if (lane <= 62) cdf[64 + lane] = c1 * itot;
  LDS_FENCE();

  // ---- deterministic inverse-CDF sampling (branchless bitwise search) ----
  float nzloc[2];
  #pragma unroll
  for (int s = 0; s < 2; ++s) {
    int i = lane + 64 * s;
    float u = ((float)i + 0.5f) * (1.0f / UU);
    int pos = 0;                       // count of cdf[0..126] <= u  (n=127)
    #pragma unroll
    for (int bit = 64; bit >= 1; bit >>= 1) {
      float c = cdf[pos + bit - 1];    // probe <= 126
      pos += (c <= u) ? bit : 0;
    }
    int ind = pos;                     // in [1,127] since cdf[0]=0
    int below = ind - 1;
    int above = (ind < UU - 2) ? ind : (UU - 2);
    float cb = cdf[below], ca = cdf[above];
    float denom = ca - cb;
    if (denom < 1e-5f) denom = 1.0f;
    float t = (u - cb) * frcp(denom);
    float bb = 0.5f * (zc[below] + zc[below + 1]);
    float ba = 0.5f * (zc[above] + zc[above + 1]);
    float zn = __builtin_fmaf(t, ba - bb, bb);
    nzloc[s] = zn;
    nz[i] = zn;
  }
  LDS_FENCE();

  // ---- sigma at the new samples (only 128 new MLP evals) ----
  float sgn[2];
  mlp_sigma<2>(nzloc, cg, w2r, b2v, sgn);

  // ---- merge-by-rank of sorted zc[128] and nz[128] into zall[256],
  //      scattering sigma alongside (fine pass reuses coarse sigma!) ----
  #pragma unroll
  for (int s = 0; s < 2; ++s) {
    int i = lane + 64 * s;
    // rank of zc[i]: count nz[j] < zc[i]
    float a = zloc[s];
    int ca_ = 0;
    #pragma unroll
    for (int bit = 64; bit >= 1; bit >>= 1) {
      float vb = nz[ca_ + bit - 1];    // probes indices 0..126
      ca_ += (vb < a) ? bit : 0;
    }
    ca_ += ((ca_ == 127) && (nz[127] < a)) ? 1 : 0;
    zall[i + ca_] = a;
    gall[i + ca_] = sgc[s];
    // rank of nz[i]: count zc[j] <= nz[i]
    float bvl = nzloc[s];
    int cb_ = 0;
    #pragma unroll
    for (int bit = 64; bit >= 1; bit >>= 1) {
      float vb = zc[cb_ + bit - 1];
      cb_ += (vb <= bvl) ? bit : 0;
    }
    cb_ += ((cb_ == 127) && (zc[127] <= bvl)) ? 1 : 0;
    zall[i + cb_] = bvl;
    gall[i + cb_] = sgn[s];
  }
  LDS_FENCE();

  // ---- fine pass: sum sigma * delta over 256 samples (no MLP) ----
  float local = 0.0f;
  #pragma unroll
  for (int s = 0; s < 4; ++s) {
    int k = lane + 64 * s;
    float zv = zall[k];
    float sg = gall[k];
    float dlt = (k < 2 * UU - 1) ? (zall[k + 1] - zv) : sd;
    local = __builtin_fmaf(sg, dlt, local);
  }
  float tsum = readlane63(wscan_add(local));
  if (active && lane == 0) out[ray] = fexp2(NLOG2E_F * tsum);
}

extern "C" void kernel_launch(void* const* d_in, const int* in_sizes, int n_in,
                              void* d_out, int out_size, void* d_ws, size_t ws_size,
                              hipStream_t stream) {
  const float* rays_o = (const float*)d_in[0];
  const float* rays_d = (const float*)d_in[1];
  const float* nearp  = (const float*)d_in[2];
  const float* farp   = (const float*)d_in[3];
  const float* noise  = (const float*)d_in[4];
  const float* W1     = (const float*)d_in[5];
  const float* b1     = (const float*)d_in[6];
  const float* W2     = (const float*)d_in[7];
  const float* b2     = (const float*)d_in[8];
  float* out = (float*)d_out;
  const int nrays = in_sizes[2];
  const int blocks = (nrays + WPB - 1) / WPB;
  nerf_transmittance_kernel<<<blocks, 256, 0, stream>>>(
      rays_o, rays_d, nearp, farp, noise, W1, b1, W2, b2, out, nrays);
}

// Round 6
// 40.098 us; speedup vs baseline: 7.7561x; 2.1174x over previous
//
#include <hip/hip_runtime.h>

#define UU 128          // coarse sample count
#define HH 32           // hidden width
#define WPB 4           // waves per block
#define NNOD 64         // sigma interpolation nodes per ray (1 per lane)

#define NLOG2E_F  (-1.44269504088896f)
#define TWOLOG2E_F  2.88539008177793f
#define LN2_F       0.693147180559945f

__device__ __forceinline__ float fexp2(float x){ return __builtin_amdgcn_exp2f(x); }
__device__ __forceinline__ float flog2(float x){ return __builtin_amdgcn_logf(x); }
__device__ __forceinline__ float frcp (float x){ return __builtin_amdgcn_rcpf(x); }
__device__ __forceinline__ float readlane63(float x){
  return __int_as_float(__builtin_amdgcn_readlane(__float_as_int(x), 63));
}

template<int CTRL, int RMASK>
__device__ __forceinline__ float dppmov(float x){
  return __int_as_float(__builtin_amdgcn_update_dpp(
      0, __float_as_int(x), CTRL, RMASK, 0xF, true));
}

// 64-lane inclusive add scan, classic gfx9 DPP pattern (no LDS pipe)
__device__ __forceinline__ float wscan_add(float v){
  v += dppmov<0x111, 0xF>(v);   // row_shr:1
  v += dppmov<0x112, 0xF>(v);   // row_shr:2
  v += dppmov<0x114, 0xF>(v);   // row_shr:4
  v += dppmov<0x118, 0xF>(v);   // row_shr:8
  v += dppmov<0x142, 0xA>(v);   // row_bcast:15 -> rows 1,3
  v += dppmov<0x143, 0xC>(v);   // row_bcast:31 -> rows 2,3
  return v;
}

// all LDS arrays are wave-private: drain DS queue + stop compiler reordering;
// same-wave DS ops execute in order, so no s_barrier needed.
#define LDS_FENCE() do { \
  asm volatile("s_waitcnt lgkmcnt(0)" ::: "memory"); \
  __builtin_amdgcn_wave_barrier(); \
} while (0)

// softplus(x) = max(x,0) + ln2*log2(1 + 2^(-log2e*|x|))
__device__ __forceinline__ float softplus_f(float x){
  float e = fexp2(NLOG2E_F * __builtin_fabsf(x));
  return __builtin_fmaxf(x, 0.0f) + LN2_F * flog2(1.0f + e);
}

// Catmull-Rom interpolation of sigma from the 64-node table (clamped edges).
// t01 = (z - z0) * invh, guaranteed ~[0, 63].
__device__ __forceinline__ float interp_sigma(const float* nod, float z,
                                              float z0, float invh){
  float t = __builtin_fmaxf((z - z0) * invh, 0.0f);
  int i = (int)t;
  i = (i < 62) ? i : 62;
  float f = t - (float)i;
  int im1 = (i > 0) ? (i - 1) : 0;
  int ip2 = (i < 61) ? (i + 2) : 63;
  float s0 = nod[im1], s1 = nod[i], s2 = nod[i + 1], s3 = nod[ip2];
  float a3 = __builtin_fmaf(1.5f, s1 - s2, 0.5f * (s3 - s0));
  float a2 = __builtin_fmaf(-2.5f, s1, s0) + __builtin_fmaf(-0.5f, s3, 2.0f * s2);
  float a1 = 0.5f * (s2 - s0);
  float p = __builtin_fmaf(__builtin_fmaf(__builtin_fmaf(a3, f, a2), f, a1), f, s1);
  return __builtin_fmaxf(p, 0.0f);   // true sigma > 0; kill CR undershoot
}

__global__ __launch_bounds__(256) void nerf_transmittance_kernel(
    const float* __restrict__ rays_o, const float* __restrict__ rays_d,
    const float* __restrict__ nearp, const float* __restrict__ farp,
    const float* __restrict__ noise, const float* __restrict__ W1,
    const float* __restrict__ b1, const float* __restrict__ W2,
    const float* __restrict__ b2, float* __restrict__ out, int nrays) {
  __shared__ float2 scg [WPB][HH];      // per-ray {c2,g2} (2log2e-scaled)
  __shared__ float  snod[WPB][NNOD];    // sigma at grid nodes
  __shared__ float  szc [WPB][UU];      // coarse z (sorted)
  __shared__ float  scdf[WPB][UU];      // cdf[0..126]
  __shared__ float  snz [WPB][UU];      // importance samples (sorted)
  __shared__ float  szall[WPB][2 * UU]; // merged z
  __shared__ float  sgall[WPB][2 * UU]; // merged sigma

  const int tid  = threadIdx.x;
  const int wave = tid >> 6;
  const int lane = tid & 63;
  const int ray  = blockIdx.x * WPB + wave;
  const bool active = ray < nrays;
  const int r = active ? ray : (nrays - 1);

  const float ox = rays_o[3*r+0], oy = rays_o[3*r+1], oz = rays_o[3*r+2];
  const float dx = rays_d[3*r+0], dy = rays_d[3*r+1], dz = rays_d[3*r+2];
  const float nv = nearp[r], fv = farp[r];
  const float sd = (fv - nv) * (1.0f / UU);

  // W2/b2 uniform: base = b2 + sum(w2); per-unit n2w2 = -2*w2 (SGPRs)
  float n2w2[HH];
  float base = b2[0];
  #pragma unroll
  for (int j = 0; j < HH; ++j) {
    float w2 = W2[j];
    base += w2;
    n2w2[j] = -2.0f * w2;
  }

  float2* cg  = scg[wave];
  float* nod  = snod[wave];
  float* zc   = szc[wave];
  float* cdf  = scdf[wave];
  float* nz   = snz[wave];
  float* zall = szall[wave];
  float* gall = sgall[wave];

  // ---- per-ray affine fold: pre_j(z) = c_j + g_j*z, scaled by 2log2e ----
  if (lane < HH) {
    float wx = W1[lane], wy = W1[HH + lane], wz = W1[2*HH + lane];
    float g = dx*wx + dy*wy + dz*wz;
    float c = ox*wx + oy*wy + oz*wz + b1[lane];
    cg[lane] = make_float2(TWOLOG2E_F * c, TWOLOG2E_F * g);
  }

  // ---- coarse z (stratified jitter) ----
  float zloc[2];
  #pragma unroll
  for (int s = 0; s < 2; ++s) {
    int i = lane + 64 * s;
    float tl = (float)i * (1.0f / (UU - 1));
    float zv = __builtin_fmaf(fv - nv, tl, nv)
             + (noise[(size_t)r * UU + i] - 0.5f) * sd;
    zloc[s] = zv;
    zc[i] = zv;
  }
  LDS_FENCE();

  // ---- sigma node table: one MLP eval per lane (64 nodes over z-range) ----
  const float z0   = nv - 0.5f * sd;
  const float span = (fv - nv) + sd;          // [nv-sd/2, fv+sd/2]
  const float h    = span * (1.0f / (NNOD - 1));
  const float invh = (float)(NNOD - 1) * frcp(span);
  {
    float zn = __builtin_fmaf((float)lane, h, z0);
    float acc = base;
    #pragma unroll
    for (int j = 0; j < HH; ++j) {
      const float2 c = cg[j];                 // ds_read_b64 broadcast
      float q = __builtin_fmaf(c.y, zn, c.x); // 2log2e * pre (signed)
      float e = fexp2(q);                     // inf-safe
      float rr = frcp(1.0f + e);              // tanh = 1 - 2r
      acc = __builtin_fmaf(n2w2[j], rr, acc);
    }
    nod[lane] = softplus_f(acc);
  }
  LDS_FENCE();

  // ---- coarse density via interpolation ----
  float sgc[2];
  sgc[0] = interp_sigma(nod, zloc[0], z0, invh);
  sgc[1] = interp_sigma(nod, zloc[1], z0, invh);

  // a_i = delta_i * sigma_i
  float d0 = zc[lane + 1] - zloc[0];                       // lane+1 <= 64
  float d1 = (lane < 63) ? (zc[lane + 65] - zloc[1]) : sd;
  float a0 = d0 * sgc[0];
  float a1 = d1 * sgc[1];

  // prefix sums (inclusive) of a over the 128 samples
  float S0 = wscan_add(a0);
  float S1 = wscan_add(a1) + readlane63(S0);

  // weights: w_i = T_excl - T_incl = exp2(-log2e*(S-a)) - exp2(-log2e*S)
  float w0 = fexp2(NLOG2E_F * (S0 - a0)) - fexp2(NLOG2E_F * S0);
  float w1 = fexp2(NLOG2E_F * (S1 - a1)) - fexp2(NLOG2E_F * S1);

  // ---- cdf over pdf elements 1..126 ----
  float v0 = (lane >= 1)  ? (w0 + 1e-5f) : 0.0f;
  float v1 = (lane <= 62) ? (w1 + 1e-5f) : 0.0f;
  float c0 = wscan_add(v0);
  float c1 = wscan_add(v1) + readlane63(c0);
  float tot = readlane63(c1);
  float itot = frcp(tot);
  cdf[lane] = c0 * itot;
  if (lane <= 62) cdf[64 + lane] = c1 * itot;
  LDS_FENCE();

  // ---- deterministic inverse-CDF sampling (branchless bitwise search) ----
  float nzloc[2];
  #pragma unroll
  for (int s = 0; s < 2; ++s) {
    int i = lane + 64 * s;
    float u = ((float)i + 0.5f) * (1.0f / UU);
    int pos = 0;                       // count of cdf[0..126] <= u  (n=127)
    #pragma unroll
    for (int bit = 64; bit >= 1; bit >>= 1) {
      float c = cdf[pos + bit - 1];    // probe <= 126
      pos += (c <= u) ? bit : 0;
    }
    int ind = pos;                     // in [1,127] since cdf[0]=0
    int below = ind - 1;
    int above = (ind < UU - 2) ? ind : (UU - 2);
    float cb = cdf[below], ca = cdf[above];
    float denom = ca - cb;
    if (denom < 1e-5f) denom = 1.0f;
    float t = (u - cb) * frcp(denom);
    float bb = 0.5f * (zc[below] + zc[below + 1]);
    float ba = 0.5f * (zc[above] + zc[above + 1]);
    float zn = __builtin_fmaf(t, ba - bb, bb);
    nzloc[s] = zn;
    nz[i] = zn;
  }
  LDS_FENCE();

  // ---- sigma at the new samples via interpolation ----
  float sgn[2];
  sgn[0] = interp_sigma(nod, nzloc[0], z0, invh);
  sgn[1] = interp_sigma(nod, nzloc[1], z0, invh);

  // ---- merge-by-rank of sorted zc[128] and nz[128] into zall[256],
  //      scattering sigma alongside ----
  #pragma unroll
  for (int s = 0; s < 2; ++s) {
    int i = lane + 64 * s;
    // rank of zc[i]: count nz[j] < zc[i]
    float a = zloc[s];
    int ca_ = 0;
    #pragma unroll
    for (int bit = 64; bit >= 1; bit >>= 1) {
      float vb = nz[ca_ + bit - 1];    // probes indices 0..126
      ca_ += (vb < a) ? bit : 0;
    }
    ca_ += ((ca_ == 127) && (nz[127] < a)) ? 1 : 0;
    zall[i + ca_] = a;
    gall[i + ca_] = sgc[s];
    // rank of nz[i]: count zc[j] <= nz[i]
    float bvl = nzloc[s];
    int cb_ = 0;
    #pragma unroll
    for (int bit = 64; bit >= 1; bit >>= 1) {
      float vb = zc[cb_ + bit - 1];
      cb_ += (vb <= bvl) ? bit : 0;
    }
    cb_ += ((cb_ == 127) && (zc[127] <= bvl)) ? 1 : 0;
    zall[i + cb_] = bvl;
    gall[i + cb_] = sgn[s];
  }
  LDS_FENCE();

  // ---- fine pass: sum sigma * delta over 256 samples (no MLP) ----
  float local = 0.0f;
  #pragma unroll
  for (int s = 0; s < 4; ++s) {
    int k = lane + 64 * s;
    float zv = zall[k];
    float sg = gall[k];
    float dlt = (k < 2 * UU - 1) ? (zall[k + 1] - zv) : sd;
    local = __builtin_fmaf(sg, dlt, local);
  }
  float tsum = readlane63(wscan_add(local));
  if (active && lane == 0) out[ray] = fexp2(NLOG2E_F * tsum);
}

extern "C" void kernel_launch(void* const* d_in, const int* in_sizes, int n_in,
                              void* d_out, int out_size, void* d_ws, size_t ws_size,
                              hipStream_t stream) {
  const float* rays_o = (const float*)d_in[0];
  const float* rays_d = (const float*)d_in[1];
  const float* nearp  = (const float*)d_in[2];
  const float* farp   = (const float*)d_in[3];
  const float* noise  = (const float*)d_in[4];
  const float* W1     = (const float*)d_in[5];
  const float* b1     = (const float*)d_in[6];
  const float* W2     = (const float*)d_in[7];
  const float* b2     = (const float*)d_in[8];
  float* out = (float*)d_out;
  const int nrays = in_sizes[2];
  const int blocks = (nrays + WPB - 1) / WPB;
  nerf_transmittance_kernel<<<blocks, 256, 0, stream>>>(
      rays_o, rays_d, nearp, farp, noise, W1, b1, W2, b2, out, nrays);
}

// Round 7
// 35.152 us; speedup vs baseline: 8.8474x; 1.1407x over previous
//
#include <hip/hip_runtime.h>

#define UU 128          // coarse sample count
#define HH 32           // hidden width
#define WPB 4           // waves per block
#define NNOD 64         // sigma interpolation nodes per ray (1 per lane)

#define NLOG2E_F  (-1.44269504088896f)
#define TWOLOG2E_F  2.88539008177793f
#define LN2_F       0.693147180559945f

__device__ __forceinline__ float fexp2(float x){ return __builtin_amdgcn_exp2f(x); }
__device__ __forceinline__ float flog2(float x){ return __builtin_amdgcn_logf(x); }
__device__ __forceinline__ float frcp (float x){ return __builtin_amdgcn_rcpf(x); }
template<int L>
__device__ __forceinline__ float readlaneN(float x){
  return __int_as_float(__builtin_amdgcn_readlane(__float_as_int(x), L));
}

template<int CTRL, int RMASK>
__device__ __forceinline__ float dppmov(float x){
  return __int_as_float(__builtin_amdgcn_update_dpp(
      0, __float_as_int(x), CTRL, RMASK, 0xF, true));
}

// 64-lane inclusive add scan, classic gfx9 DPP pattern (no LDS pipe)
__device__ __forceinline__ float wscan_add(float v){
  v += dppmov<0x111, 0xF>(v);   // row_shr:1
  v += dppmov<0x112, 0xF>(v);   // row_shr:2
  v += dppmov<0x114, 0xF>(v);   // row_shr:4
  v += dppmov<0x118, 0xF>(v);   // row_shr:8
  v += dppmov<0x142, 0xA>(v);   // row_bcast:15 -> rows 1,3
  v += dppmov<0x143, 0xC>(v);   // row_bcast:31 -> rows 2,3
  return v;
}

// all LDS arrays are wave-private: drain DS queue + stop compiler reordering;
// same-wave DS ops execute in order, so no s_barrier needed.
#define LDS_FENCE() do { \
  asm volatile("s_waitcnt lgkmcnt(0)" ::: "memory"); \
  __builtin_amdgcn_wave_barrier(); \
} while (0)

// softplus(x) = max(x,0) + ln2*log2(1 + 2^(-log2e*|x|))
__device__ __forceinline__ float softplus_f(float x){
  float e = fexp2(NLOG2E_F * __builtin_fabsf(x));
  return __builtin_fmaxf(x, 0.0f) + LN2_F * flog2(1.0f + e);
}

// Catmull-Rom interpolation from the padded 66-entry node table.
// pad[0]=node0, pad[1..64]=nodes, pad[65]=node63 (edge clamps via duplication).
__device__ __forceinline__ float interp_sigma(const float* pad, float z,
                                              float z0, float invh){
  float t = __builtin_fmaxf((z - z0) * invh, 0.0f);
  int i = (int)t;
  i = (i < 62) ? i : 62;
  float f = t - (float)i;
  float s0 = pad[i], s1 = pad[i + 1], s2 = pad[i + 2], s3 = pad[i + 3];
  float a3 = __builtin_fmaf(1.5f, s1 - s2, 0.5f * (s3 - s0));
  float a2 = __builtin_fmaf(-2.5f, s1, s0) + __builtin_fmaf(-0.5f, s3, 2.0f * s2);
  float a1 = 0.5f * (s2 - s0);
  float p = __builtin_fmaf(__builtin_fmaf(__builtin_fmaf(a3, f, a2), f, a1), f, s1);
  return __builtin_fmaxf(p, 0.0f);   // true sigma > 0; kill CR undershoot
}

__global__ __launch_bounds__(256) void nerf_transmittance_kernel(
    const float* __restrict__ rays_o, const float* __restrict__ rays_d,
    const float* __restrict__ nearp, const float* __restrict__ farp,
    const float* __restrict__ noise, const float* __restrict__ W1,
    const float* __restrict__ b1, const float* __restrict__ W2,
    const float* __restrict__ b2, float* __restrict__ out, int nrays) {
  __shared__ float2 scg [WPB][HH];       // per-ray {c2,g2} (2log2e-scaled)
  __shared__ float  snod[WPB][NNOD + 2]; // padded sigma node table
  __shared__ float  szc [WPB][UU];       // coarse z (sorted)
  __shared__ float  scdf[WPB][UU];       // cdf[0..126]
  __shared__ float  snz [WPB][UU];       // importance samples (sorted)
  __shared__ float  szall[WPB][2 * UU];  // merged z
  __shared__ float  sgall[WPB][2 * UU];  // merged sigma

  const int tid  = threadIdx.x;
  const int wave = tid >> 6;
  const int lane = tid & 63;
  const int ray  = blockIdx.x * WPB + wave;
  const bool active = ray < nrays;
  const int r = active ? ray : (nrays - 1);

  const float ox = rays_o[3*r+0], oy = rays_o[3*r+1], oz = rays_o[3*r+2];
  const float dx = rays_d[3*r+0], dy = rays_d[3*r+1], dz = rays_d[3*r+2];
  const float nv = nearp[r], fv = farp[r];
  const float sd = (fv - nv) * (1.0f / UU);

  // W2/b2 uniform: base = b2 + sum(w2); per-unit n2w2 = -2*w2 (SGPRs)
  float n2w2[HH];
  float base = b2[0];
  #pragma unroll
  for (int j = 0; j < HH; ++j) {
    float w2 = W2[j];
    base += w2;
    n2w2[j] = -2.0f * w2;
  }

  float2* cg  = scg[wave];
  float* nod  = snod[wave];   // padded: [0]=dup, [1..64]=nodes, [65]=dup
  float* zc   = szc[wave];
  float* cdf  = scdf[wave];
  float* nz   = snz[wave];
  float* zall = szall[wave];
  float* gall = sgall[wave];

  // ---- per-ray affine fold: pre_j(z) = c_j + g_j*z, scaled by 2log2e ----
  if (lane < HH) {
    float wx = W1[lane], wy = W1[HH + lane], wz = W1[2*HH + lane];
    float g = dx*wx + dy*wy + dz*wz;
    float c = ox*wx + oy*wy + oz*wz + b1[lane];
    cg[lane] = make_float2(TWOLOG2E_F * c, TWOLOG2E_F * g);
  }

  // ---- coarse z (stratified jitter) ----
  float zloc[2];
  #pragma unroll
  for (int s = 0; s < 2; ++s) {
    int i = lane + 64 * s;
    float tl = (float)i * (1.0f / (UU - 1));
    float zv = __builtin_fmaf(fv - nv, tl, nv)
             + (noise[(size_t)r * UU + i] - 0.5f) * sd;
    zloc[s] = zv;
    zc[i] = zv;
  }
  LDS_FENCE();

  // ---- sigma node table: one MLP eval per lane (64 nodes over z-range) ----
  const float z0   = nv - 0.5f * sd;
  const float span = (fv - nv) + sd;          // [nv-sd/2, fv+sd/2]
  const float h    = span * (1.0f / (NNOD - 1));
  const float invh = (float)(NNOD - 1) * frcp(span);
  {
    float zn = __builtin_fmaf((float)lane, h, z0);
    float acc = base;
    #pragma unroll
    for (int j = 0; j < HH; ++j) {
      const float2 c = cg[j];                 // ds_read_b64 broadcast
      float q = __builtin_fmaf(c.y, zn, c.x); // 2log2e * pre (signed)
      float e = fexp2(q);                     // inf-safe
      float rr = frcp(1.0f + e);              // tanh = 1 - 2r
      acc = __builtin_fmaf(n2w2[j], rr, acc);
    }
    float sgn_ = softplus_f(acc);
    nod[1 + lane] = sgn_;
    if (lane == 0)  nod[0]  = sgn_;           // pad left
    if (lane == 63) nod[65] = sgn_;           // pad right
  }
  LDS_FENCE();

  // ---- coarse density via interpolation ----
  float sgc[2];
  sgc[0] = interp_sigma(nod, zloc[0], z0, invh);
  sgc[1] = interp_sigma(nod, zloc[1], z0, invh);

  // a_i = delta_i * sigma_i; inclusive prefix S
  float d0 = zc[lane + 1] - zloc[0];                       // lane+1 <= 64
  float d1 = (lane < 63) ? (zc[lane + 65] - zloc[1]) : sd;
  float a0 = d0 * sgc[0];
  float a1 = d1 * sgc[1];
  float S0 = wscan_add(a0);
  float S1 = wscan_add(a1) + readlaneN<63>(S0);

  // T_incl(i) = exp2(-log2e * S_i)
  float Ti0 = fexp2(NLOG2E_F * S0);
  float Ti1 = fexp2(NLOG2E_F * S1);

  // ---- telescoped cdf: cumsum(w)_1..i = Texcl(1) - Tincl(i);
  //      cdf_i = (T1x - T_i + i*1e-5) / (T1x - T_126 + 126e-5) ----
  float T1x   = readlaneN<0>(Ti0);    // Texcl(1) = Tincl(0)
  float T126  = readlaneN<62>(Ti1);   // Tincl(126)
  float itot  = frcp(T1x - T126 + 126.0f * 1e-5f);
  float lanef = (float)lane;
  cdf[lane] = (T1x - Ti0 + lanef * 1e-5f) * itot;           // i = 0..63
  if (lane <= 62)
    cdf[64 + lane] = (T1x - Ti1 + (lanef + 64.0f) * 1e-5f) * itot; // 64..126
  LDS_FENCE();

  // ---- deterministic inverse-CDF sampling (branchless bitwise search) ----
  float nzloc[2], zcb1R[2];
  int   belowR[2];
  #pragma unroll
  for (int s = 0; s < 2; ++s) {
    int i = lane + 64 * s;
    float u = ((float)i + 0.5f) * (1.0f / UU);
    int pos = 0;                       // count of cdf[0..126] <= u  (n=127)
    #pragma unroll
    for (int bit = 64; bit >= 1; bit >>= 1) {
      float c = cdf[pos + bit - 1];    // probe <= 126
      pos += (c <= u) ? bit : 0;
    }
    int ind = pos;                     // in [1,127] since cdf[0]=0
    int below = ind - 1;
    int above = (ind < UU - 2) ? ind : (UU - 2);
    float cb = cdf[below], ca = cdf[above];
    float denom = ca - cb;
    if (denom < 1e-5f) denom = 1.0f;
    float t = (u - cb) * frcp(denom);
    float zb0 = zc[below], zb1 = zc[below + 1];
    float bb = 0.5f * (zb0 + zb1);
    float ba = 0.5f * (zc[above] + zc[above + 1]);
    float zn = __builtin_fmaf(t, ba - bb, bb);
    nzloc[s] = zn;
    belowR[s] = below;
    zcb1R[s] = zb1;
    nz[i] = zn;
  }
  LDS_FENCE();

  // ---- sigma at the new samples via interpolation ----
  float sgn[2];
  sgn[0] = interp_sigma(nod, nzloc[0], z0, invh);
  sgn[1] = interp_sigma(nod, nzloc[1], z0, invh);

  // ---- merge of sorted zc[128] and nz[128] into zall[256] ----
  // zc side: 7-probe rank search in nz. nz side: analytic rank —
  // nz_i in [z_mid[b], z_mid[b+1]] => rank in zc = b+1+(zc[b+1] <= nz_i).
  #pragma unroll
  for (int s = 0; s < 2; ++s) {
    int i = lane + 64 * s;
    float a = zloc[s];
    int ca_ = 0;
    #pragma unroll
    for (int bit = 64; bit >= 1; bit >>= 1) {
      float vb = nz[ca_ + bit - 1];    // probes indices 0..126
      ca_ += (vb < a) ? bit : 0;
    }
    ca_ += ((ca_ == 127) && (nz[127] < a)) ? 1 : 0;
    zall[i + ca_] = a;
    gall[i + ca_] = sgc[s];

    int pb = i + belowR[s] + 1 + ((zcb1R[s] <= nzloc[s]) ? 1 : 0);
    zall[pb] = nzloc[s];
    gall[pb] = sgn[s];
  }
  LDS_FENCE();

  // ---- fine pass: sum sigma * delta over 256 samples (no MLP) ----
  float local = 0.0f;
  #pragma unroll
  for (int s = 0; s < 4; ++s) {
    int k = lane + 64 * s;
    float zv = zall[k];
    float sg = gall[k];
    float dlt = (k < 2 * UU - 1) ? (zall[k + 1] - zv) : sd;
    local = __builtin_fmaf(sg, dlt, local);
  }
  float tsum = readlaneN<63>(wscan_add(local));
  if (active && lane == 0) out[ray] = fexp2(NLOG2E_F * tsum);
}

extern "C" void kernel_launch(void* const* d_in, const int* in_sizes, int n_in,
                              void* d_out, int out_size, void* d_ws, size_t ws_size,
                              hipStream_t stream) {
  const float* rays_o = (const float*)d_in[0];
  const float* rays_d = (const float*)d_in[1];
  const float* nearp  = (const float*)d_in[2];
  const float* farp   = (const float*)d_in[3];
  const float* noise  = (const float*)d_in[4];
  const float* W1     = (const float*)d_in[5];
  const float* b1     = (const float*)d_in[6];
  const float* W2     = (const float*)d_in[7];
  const float* b2     = (const float*)d_in[8];
  float* out = (float*)d_out;
  const int nrays = in_sizes[2];
  const int blocks = (nrays + WPB - 1) / WPB;
  nerf_transmittance_kernel<<<blocks, 256, 0, stream>>>(
      rays_o, rays_d, nearp, farp, noise, W1, b1, W2, b2, out, nrays);
}

// Round 8
// 34.995 us; speedup vs baseline: 8.8871x; 1.0045x over previous
//
#include <hip/hip_runtime.h>

#define UU 128          // coarse sample count
#define HH 32           // hidden width
#define WPB 4           // waves per block
#define NNOD 64         // sigma interpolation nodes per ray (1 per lane)

#define NLOG2E_F  (-1.44269504088896f)
#define TWOLOG2E_F  2.88539008177793f
#define LN2_F       0.693147180559945f

__device__ __forceinline__ float fexp2(float x){ return __builtin_amdgcn_exp2f(x); }
__device__ __forceinline__ float flog2(float x){ return __builtin_amdgcn_logf(x); }
__device__ __forceinline__ float frcp (float x){ return __builtin_amdgcn_rcpf(x); }
template<int L>
__device__ __forceinline__ float readlaneN(float x){
  return __int_as_float(__builtin_amdgcn_readlane(__float_as_int(x), L));
}

template<int CTRL, int RMASK>
__device__ __forceinline__ float dppmov(float x){
  return __int_as_float(__builtin_amdgcn_update_dpp(
      0, __float_as_int(x), CTRL, RMASK, 0xF, true));
}

// 64-lane inclusive add scan, classic gfx9 DPP pattern (no LDS pipe)
__device__ __forceinline__ float wscan_add(float v){
  v += dppmov<0x111, 0xF>(v);   // row_shr:1
  v += dppmov<0x112, 0xF>(v);   // row_shr:2
  v += dppmov<0x114, 0xF>(v);   // row_shr:4
  v += dppmov<0x118, 0xF>(v);   // row_shr:8
  v += dppmov<0x142, 0xA>(v);   // row_bcast:15 -> rows 1,3
  v += dppmov<0x143, 0xC>(v);   // row_bcast:31 -> rows 2,3
  return v;
}

// all LDS arrays are wave-private: drain DS queue + stop compiler reordering;
// same-wave DS ops execute in order, so no s_barrier needed.
#define LDS_FENCE() do { \
  asm volatile("s_waitcnt lgkmcnt(0)" ::: "memory"); \
  __builtin_amdgcn_wave_barrier(); \
} while (0)

// softplus(x) = max(x,0) + ln2*log2(1 + 2^(-log2e*|x|))
__device__ __forceinline__ float softplus_f(float x){
  float e = fexp2(NLOG2E_F * __builtin_fabsf(x));
  return __builtin_fmaxf(x, 0.0f) + LN2_F * flog2(1.0f + e);
}

// Catmull-Rom interpolation from the padded 66-entry node table.
__device__ __forceinline__ float interp_sigma(const float* pad, float z,
                                              float z0, float invh){
  float t = __builtin_fmaxf((z - z0) * invh, 0.0f);
  int i = (int)t;
  i = (i < 62) ? i : 62;
  float f = t - (float)i;
  float s0 = pad[i], s1 = pad[i + 1], s2 = pad[i + 2], s3 = pad[i + 3];
  float a3 = __builtin_fmaf(1.5f, s1 - s2, 0.5f * (s3 - s0));
  float a2 = __builtin_fmaf(-2.5f, s1, s0) + __builtin_fmaf(-0.5f, s3, 2.0f * s2);
  float a1 = 0.5f * (s2 - s0);
  float p = __builtin_fmaf(__builtin_fmaf(__builtin_fmaf(a3, f, a2), f, a1), f, s1);
  return __builtin_fmaxf(p, 0.0f);   // true sigma > 0; kill CR undershoot
}

__global__ __launch_bounds__(256) void nerf_transmittance_kernel(
    const float* __restrict__ rays_o, const float* __restrict__ rays_d,
    const float* __restrict__ nearp, const float* __restrict__ farp,
    const float* __restrict__ noise, const float* __restrict__ W1,
    const float* __restrict__ b1, const float* __restrict__ W2,
    const float* __restrict__ b2, float* __restrict__ out, int nrays) {
  __shared__ float2 scg  [WPB][HH];       // per-ray {c2,g2} (2log2e-scaled)
  __shared__ float  snod [WPB][NNOD + 2]; // padded sigma node table
  __shared__ float2 szcdf[WPB][UU];       // interleaved (zc_k, cdf_k)
  __shared__ float  snz  [WPB][UU];       // importance samples (sorted)
  __shared__ float2 szg  [WPB][2 * UU];   // merged (z, sigma)

  const int tid  = threadIdx.x;
  const int wave = tid >> 6;
  const int lane = tid & 63;
  const int ray  = blockIdx.x * WPB + wave;
  const bool active = ray < nrays;
  const int r = active ? ray : (nrays - 1);

  const float ox = rays_o[3*r+0], oy = rays_o[3*r+1], oz = rays_o[3*r+2];
  const float dx = rays_d[3*r+0], dy = rays_d[3*r+1], dz = rays_d[3*r+2];
  const float nv = nearp[r], fv = farp[r];
  const float sd = (fv - nv) * (1.0f / UU);

  // W2/b2 uniform: base = b2 + sum(w2); per-unit n2w2 = -2*w2 (SGPRs)
  float n2w2[HH];
  float base = b2[0];
  #pragma unroll
  for (int j = 0; j < HH; ++j) {
    float w2 = W2[j];
    base += w2;
    n2w2[j] = -2.0f * w2;
  }

  float2* cg   = scg[wave];
  float*  nod  = snod[wave];
  float2* zcdf = szcdf[wave];
  float*  nz   = snz[wave];
  float2* zg   = szg[wave];

  // ---- per-ray affine fold: pre_j(z) = c_j + g_j*z, scaled by 2log2e ----
  if (lane < HH) {
    float wx = W1[lane], wy = W1[HH + lane], wz = W1[2*HH + lane];
    float g = dx*wx + dy*wy + dz*wz;
    float c = ox*wx + oy*wy + oz*wz + b1[lane];
    cg[lane] = make_float2(TWOLOG2E_F * c, TWOLOG2E_F * g);
  }

  // ---- coarse z (stratified jitter), write .x of the pair table ----
  float zloc[2];
  #pragma unroll
  for (int s = 0; s < 2; ++s) {
    int i = lane + 64 * s;
    float tl = (float)i * (1.0f / (UU - 1));
    float zv = __builtin_fmaf(fv - nv, tl, nv)
             + (noise[(size_t)r * UU + i] - 0.5f) * sd;
    zloc[s] = zv;
    zcdf[i].x = zv;
  }
  LDS_FENCE();

  // ---- sigma node table: one MLP eval per lane (64 nodes over z-range) ----
  const float z0   = nv - 0.5f * sd;
  const float span = (fv - nv) + sd;          // [nv-sd/2, fv+sd/2]
  const float h    = span * (1.0f / (NNOD - 1));
  const float invh = (float)(NNOD - 1) * frcp(span);
  {
    float zn = __builtin_fmaf((float)lane, h, z0);
    float acc = base;
    #pragma unroll
    for (int j = 0; j < HH; ++j) {
      const float2 c = cg[j];                 // ds_read_b64 broadcast
      float q = __builtin_fmaf(c.y, zn, c.x); // 2log2e * pre (signed)
      float e = fexp2(q);                     // inf-safe
      float rr = frcp(1.0f + e);              // tanh = 1 - 2r
      acc = __builtin_fmaf(n2w2[j], rr, acc);
    }
    float sgn_ = softplus_f(acc);
    nod[1 + lane] = sgn_;
    if (lane == 0)  nod[0]  = sgn_;           // pad left
    if (lane == 63) nod[65] = sgn_;           // pad right
  }

  // deltas need zc neighbors (.x written before fence #1)
  float zn1 = zcdf[lane + 1].x;               // i+1 <= 64
  int ip65 = (lane < 63) ? (lane + 65) : 127; // clamp: value unused at lane 63
  float zn2 = zcdf[ip65].x;
  LDS_FENCE();

  // ---- coarse density via interpolation ----
  float sgc[2];
  sgc[0] = interp_sigma(nod, zloc[0], z0, invh);
  sgc[1] = interp_sigma(nod, zloc[1], z0, invh);

  // a_i = delta_i * sigma_i; inclusive prefix S
  float d0 = zn1 - zloc[0];
  float d1 = (lane < 63) ? (zn2 - zloc[1]) : sd;
  float a0 = d0 * sgc[0];
  float a1 = d1 * sgc[1];
  float S0 = wscan_add(a0);
  float S1 = wscan_add(a1) + readlaneN<63>(S0);

  // T_incl(i) = exp2(-log2e * S_i)
  float Ti0 = fexp2(NLOG2E_F * S0);
  float Ti1 = fexp2(NLOG2E_F * S1);

  // ---- telescoped cdf: cumsum(w)_1..i = Texcl(1) - Tincl(i) ----
  float T1x   = readlaneN<0>(Ti0);    // Texcl(1) = Tincl(0)
  float T126  = readlaneN<62>(Ti1);   // Tincl(126)
  float itot  = frcp(T1x - T126 + 126.0f * 1e-5f);
  float lanef = (float)lane;
  zcdf[lane].y = (T1x - Ti0 + lanef * 1e-5f) * itot;            // cdf 0..63
  if (lane <= 62)
    zcdf[64 + lane].y = (T1x - Ti1 + (lanef + 64.0f) * 1e-5f) * itot; // 64..126
  LDS_FENCE();

  // ---- deterministic inverse-CDF sampling ----
  // cdf[126] = x*rcp(x) ~= 1.0 > u_max = 1-1/256 always => ind <= 126,
  // so above = below+1 unconditionally and below+2 <= 127.
  float nzloc[2], zcb1R[2];
  int   belowR[2];
  #pragma unroll
  for (int s = 0; s < 2; ++s) {
    int i = lane + 64 * s;
    float u = ((float)i + 0.5f) * (1.0f / UU);
    int pos = 0;                       // count of cdf[0..126] <= u  (n=127)
    #pragma unroll
    for (int bit = 64; bit >= 1; bit >>= 1) {
      float c = zcdf[pos + bit - 1].y; // probe <= 126
      pos += (c <= u) ? bit : 0;
    }
    int below = pos - 1;               // in [0,125]
    float2 pb0 = zcdf[below];          // (zc[b],   cdf[b])
    float2 pb1 = zcdf[below + 1];      // (zc[b+1], cdf[b+1])
    float2 pb2 = zcdf[below + 2];      // (zc[b+2], unused)
    float denom = pb1.y - pb0.y;
    if (denom < 1e-5f) denom = 1.0f;
    float t = (u - pb0.y) * frcp(denom);
    float bb = 0.5f * (pb0.x + pb1.x);
    float ba = 0.5f * (pb1.x + pb2.x);
    float zn = __builtin_fmaf(t, ba - bb, bb);
    nzloc[s] = zn;
    belowR[s] = below;
    zcb1R[s] = pb1.x;
    nz[i] = zn;
  }
  LDS_FENCE();

  // ---- sigma at the new samples via interpolation ----
  float sgn[2];
  sgn[0] = interp_sigma(nod, nzloc[0], z0, invh);
  sgn[1] = interp_sigma(nod, nzloc[1], z0, invh);

  // ---- merge of sorted zc[128] and nz[128] into zg[256] ----
  // zc side: 7-probe rank search in nz. nz side: analytic rank —
  // nz_i in [z_mid[b], z_mid[b+1]] => rank in zc = b+1+(zc[b+1] <= nz_i).
  #pragma unroll
  for (int s = 0; s < 2; ++s) {
    int i = lane + 64 * s;
    float a = zloc[s];
    int ca_ = 0;
    #pragma unroll
    for (int bit = 64; bit >= 1; bit >>= 1) {
      float vb = nz[ca_ + bit - 1];    // probes indices 0..126
      ca_ += (vb < a) ? bit : 0;
    }
    ca_ += ((ca_ == 127) && (nz[127] < a)) ? 1 : 0;
    zg[i + ca_] = make_float2(a, sgc[s]);

    int pb = i + belowR[s] + 1 + ((zcb1R[s] <= nzloc[s]) ? 1 : 0);
    zg[pb] = make_float2(nzloc[s], sgn[s]);
  }
  LDS_FENCE();

  // ---- fine pass: sum sigma * delta over 256 merged samples ----
  float local = 0.0f;
  #pragma unroll
  for (int s = 0; s < 4; ++s) {
    int k = lane + 64 * s;
    int kp = (k < 2 * UU - 1) ? (k + 1) : (2 * UU - 1);
    float2 pk  = zg[k];
    float2 pk1 = zg[kp];
    float dlt = (k < 2 * UU - 1) ? (pk1.x - pk.x) : sd;
    local = __builtin_fmaf(pk.y, dlt, local);
  }
  float tsum = readlaneN<63>(wscan_add(local));
  if (active && lane == 0) out[ray] = fexp2(NLOG2E_F * tsum);
}

extern "C" void kernel_launch(void* const* d_in, const int* in_sizes, int n_in,
                              void* d_out, int out_size, void* d_ws, size_t ws_size,
                              hipStream_t stream) {
  const float* rays_o = (const float*)d_in[0];
  const float* rays_d = (const float*)d_in[1];
  const float* nearp  = (const float*)d_in[2];
  const float* farp   = (const float*)d_in[3];
  const float* noise  = (const float*)d_in[4];
  const float* W1     = (const float*)d_in[5];
  const float* b1     = (const float*)d_in[6];
  const float* W2     = (const float*)d_in[7];
  const float* b2     = (const float*)d_in[8];
  float* out = (float*)d_out;
  const int nrays = in_sizes[2];
  const int blocks = (nrays + WPB - 1) / WPB;
  nerf_transmittance_kernel<<<blocks, 256, 0, stream>>>(
      rays_o, rays_d, nearp, farp, noise, W1, b1, W2, b2, out, nrays);
}

// Round 10
// 33.721 us; speedup vs baseline: 9.2230x; 1.0378x over previous
//
#include <hip/hip_runtime.h>

#define UU 128          // coarse sample count
#define HH 32           // hidden width
#define WPB 4           // waves per block
#define NNOD 64         // sigma interpolation nodes per ray (1 per lane)

#define NLOG2E_F  (-1.44269504088896f)
#define TWOLOG2E_F  2.88539008177793f
#define LN2_F       0.693147180559945f

__device__ __forceinline__ float fexp2(float x){ return __builtin_amdgcn_exp2f(x); }
__device__ __forceinline__ float flog2(float x){ return __builtin_amdgcn_logf(x); }
__device__ __forceinline__ float frcp (float x){ return __builtin_amdgcn_rcpf(x); }
template<int L>
__device__ __forceinline__ float readlaneNf(float x){
  return __int_as_float(__builtin_amdgcn_readlane(__float_as_int(x), L));
}
template<int L>
__device__ __forceinline__ int readlaneNi(int x){
  return __builtin_amdgcn_readlane(x, L);
}

template<int CTRL, int RMASK>
__device__ __forceinline__ float dppmovf(float x){
  return __int_as_float(__builtin_amdgcn_update_dpp(
      0, __float_as_int(x), CTRL, RMASK, 0xF, true));
}
template<int CTRL, int RMASK>
__device__ __forceinline__ int dppmovi(int x){
  return __builtin_amdgcn_update_dpp(0, x, CTRL, RMASK, 0xF, true);
}

// 64-lane inclusive scans, gfx9 DPP pattern (no LDS pipe)
__device__ __forceinline__ float wscan_addf(float v){
  v += dppmovf<0x111, 0xF>(v);   // row_shr:1
  v += dppmovf<0x112, 0xF>(v);   // row_shr:2
  v += dppmovf<0x114, 0xF>(v);   // row_shr:4
  v += dppmovf<0x118, 0xF>(v);   // row_shr:8
  v += dppmovf<0x142, 0xA>(v);   // row_bcast:15 -> rows 1,3
  v += dppmovf<0x143, 0xC>(v);   // row_bcast:31 -> rows 2,3
  return v;
}
__device__ __forceinline__ int wscan_addi(int v){
  v += dppmovi<0x111, 0xF>(v);
  v += dppmovi<0x112, 0xF>(v);
  v += dppmovi<0x114, 0xF>(v);
  v += dppmovi<0x118, 0xF>(v);
  v += dppmovi<0x142, 0xA>(v);
  v += dppmovi<0x143, 0xC>(v);
  return v;
}
__device__ __forceinline__ int imax2(int a, int b){ return a > b ? a : b; }
__device__ __forceinline__ int wscan_maxi(int v){
  v = imax2(v, dppmovi<0x111, 0xF>(v));
  v = imax2(v, dppmovi<0x112, 0xF>(v));
  v = imax2(v, dppmovi<0x114, 0xF>(v));
  v = imax2(v, dppmovi<0x118, 0xF>(v));
  v = imax2(v, dppmovi<0x142, 0xA>(v));
  v = imax2(v, dppmovi<0x143, 0xC>(v));
  return v;
}

// all LDS arrays are wave-private: drain DS queue + stop compiler reordering.
#define LDS_FENCE() do { \
  asm volatile("s_waitcnt lgkmcnt(0)" ::: "memory"); \
  __builtin_amdgcn_wave_barrier(); \
} while (0)

// softplus(x) = max(x,0) + ln2*log2(1 + 2^(-log2e*|x|))
__device__ __forceinline__ float softplus_f(float x){
  float e = fexp2(NLOG2E_F * __builtin_fabsf(x));
  return __builtin_fmaxf(x, 0.0f) + LN2_F * flog2(1.0f + e);
}

// Catmull-Rom from the overlapping-pair node table P[i] = (nod[i], nod[i+1]).
__device__ __forceinline__ float interp_sigmaP(const float2* P, float z,
                                               float z0, float invh){
  float t = __builtin_fmaxf((z - z0) * invh, 0.0f);
  int i = (int)t;
  i = (i < 62) ? i : 62;
  float f = t - (float)i;
  float2 p01 = P[i];       // (nod[i],   nod[i+1])
  float2 p23 = P[i + 2];   // (nod[i+2], nod[i+3])
  float s0 = p01.x, s1 = p01.y, s2 = p23.x, s3 = p23.y;
  float a3 = __builtin_fmaf(1.5f, s1 - s2, 0.5f * (s3 - s0));
  float a2 = __builtin_fmaf(-2.5f, s1, s0) + __builtin_fmaf(-0.5f, s3, 2.0f * s2);
  float a1 = 0.5f * (s2 - s0);
  float p = __builtin_fmaf(__builtin_fmaf(__builtin_fmaf(a3, f, a2), f, a1), f, s1);
  return __builtin_fmaxf(p, 0.0f);   // kill CR undershoot (true sigma > 0)
}

__global__ __launch_bounds__(256) void nerf_transmittance_kernel(
    const float* __restrict__ rays_o, const float* __restrict__ rays_d,
    const float* __restrict__ nearp, const float* __restrict__ farp,
    const float* __restrict__ noise, const float* __restrict__ W1,
    const float* __restrict__ b1, const float* __restrict__ W2,
    const float* __restrict__ b2, float* __restrict__ out, int nrays) {
  __shared__ float2 scg  [WPB][HH];        // per-ray {c2,g2} (2log2e-scaled)
  __shared__ float2 sP   [WPB][NNOD + 2];  // overlapping node pairs [0..64]
  __shared__ float2 szcdf[WPB][UU];        // interleaved (zc_k, cdf_k)
  __shared__ int2   smkA [WPB][UU / 2];    // sampling scatter-max array (128 ints)
  __shared__ int2   smkB [WPB][UU / 2];    // merge scatter-add array (128 ints)
  __shared__ float2 szg  [WPB][2 * UU];    // merged (z, sigma)

  const int tid  = threadIdx.x;
  const int wave = tid >> 6;
  const int lane = tid & 63;
  const int ray  = blockIdx.x * WPB + wave;
  const bool active = ray < nrays;
  const int r = active ? ray : (nrays - 1);
  const int ru = __builtin_amdgcn_readfirstlane(r);   // wave-uniform -> s_loads

  const float ox = rays_o[3*ru+0], oy = rays_o[3*ru+1], oz = rays_o[3*ru+2];
  const float dx = rays_d[3*ru+0], dy = rays_d[3*ru+1], dz = rays_d[3*ru+2];
  const float nv = nearp[ru], fv = farp[ru];
  const float sd = (fv - nv) * (1.0f / UU);

  // W2/b2 uniform: base = b2 + sum(w2); per-unit n2w2 = -2*w2 (SGPRs)
  float n2w2[HH];
  float base = b2[0];
  #pragma unroll
  for (int j = 0; j < HH; ++j) {
    float w2 = W2[j];
    base += w2;
    n2w2[j] = -2.0f * w2;
  }

  float2* cg   = scg[wave];
  float2* vP   = sP[wave];
  float2* zcdf = szcdf[wave];
  int*    mkA  = (int*)smkA[wave];
  int*    mkB  = (int*)smkB[wave];
  float2* zg   = szg[wave];

  // ---- P1: zero scatter arrays; per-ray affine fold ----
  smkA[wave][lane] = make_int2(0, 0);
  smkB[wave][lane] = make_int2(0, 0);
  if (lane < HH) {
    float wx = W1[lane], wy = W1[HH + lane], wz = W1[2*HH + lane];
    float g = dx*wx + dy*wy + dz*wz;
    float c = ox*wx + oy*wy + oz*wz + b1[lane];
    cg[lane] = make_float2(TWOLOG2E_F * c, TWOLOG2E_F * g);
  }

  // coarse z (registers only) + algebraic deltas from noise
  const size_t nb = (size_t)ru * UU;
  float n_a  = noise[nb + lane];
  float n_ap = noise[nb + lane + 1];
  float n_b  = noise[nb + 64 + lane];
  int   ibp  = (lane < 63) ? (65 + lane) : 127;
  float n_bp = noise[nb + ibp];
  const float step = (fv - nv) * (1.0f / (UU - 1));
  float zloc[2];
  zloc[0] = __builtin_fmaf(step, (float)lane, nv) + (n_a - 0.5f) * sd;
  zloc[1] = __builtin_fmaf(step, (float)(64 + lane), nv) + (n_b - 0.5f) * sd;
  float d0 = step + (n_ap - n_a) * sd;
  float d1 = (lane < 63) ? (step + (n_bp - n_b) * sd) : sd;
  LDS_FENCE();

  // ---- P2: node MLP (one eval per lane), write pair table ----
  const float z0   = nv - 0.5f * sd;
  const float span = (fv - nv) + sd;
  const float h    = span * (1.0f / (NNOD - 1));
  const float invh = (float)(NNOD - 1) * frcp(span);
  {
    float zn = __builtin_fmaf((float)lane, h, z0);
    float acc = base;
    #pragma unroll
    for (int j = 0; j < HH; ++j) {
      const float2 c = cg[j];                 // ds_read_b64 broadcast
      float q = __builtin_fmaf(c.y, zn, c.x); // 2log2e * pre (signed)
      float e = fexp2(q);                     // inf-safe
      float rr = frcp(1.0f + e);              // tanh = 1 - 2r
      acc = __builtin_fmaf(n2w2[j], rr, acc);
    }
    float v = softplus_f(acc);
    // P[i] = (nod[i], nod[i+1]); nod = [v0, v0..v63, v63] (dup-padded)
    ((float*)&vP[lane + 1])[0] = v;           // P[L+1].x = nod[L+1] = v_L
    ((float*)&vP[lane])[1]     = v;           // P[L].y   = nod[L+1] = v_L
    if (lane == 0)  ((float*)&vP[0])[0]  = v; // P[0].x  = nod[0]  = v_0
    if (lane == 63) ((float*)&vP[64])[1] = v; // P[64].y = nod[65] = v_63
  }
  LDS_FENCE();

  // ---- P3: coarse sigma, scans, telescoped cdf, zcdf write, i* scatter ----
  float sgc0 = interp_sigmaP(vP, zloc[0], z0, invh);
  float sgc1 = interp_sigmaP(vP, zloc[1], z0, invh);

  float a0 = d0 * sgc0;
  float a1 = d1 * sgc1;
  float S0 = wscan_addf(a0);
  float S1 = wscan_addf(a1) + readlaneNf<63>(S0);
  float Ti0 = fexp2(NLOG2E_F * S0);
  float Ti1 = fexp2(NLOG2E_F * S1);

  float T1x  = readlaneNf<0>(Ti0);    // Texcl(1) = Tincl(0)
  float T126 = readlaneNf<62>(Ti1);   // Tincl(126)
  float itot = frcp(T1x - T126 + 126.0f * 1e-5f);
  float lanef = (float)lane;
  float cdf0 = (T1x - Ti0 + lanef * 1e-5f) * itot;            // cdf[lane]
  float cdf1 = (T1x - Ti1 + (lanef + 64.0f) * 1e-5f) * itot;  // cdf[64+lane]
  zcdf[lane]      = make_float2(zloc[0], cdf0);
  zcdf[64 + lane] = make_float2(zloc[1], cdf1);  // cdf[127] dummy, never probed

  // scatter-max: i_k* = ceil(128*cdf_k - 0.5) = first sample at/after cdf_k
  int is0 = (int)__builtin_ceilf(__builtin_fmaf(cdf0, 128.0f, -0.5f));
  if (is0 < 128) atomicMax(&mkA[is0], lane);
  int is1 = (int)__builtin_ceilf(__builtin_fmaf(cdf1, 128.0f, -0.5f));
  if (lane <= 62 && is1 < 128) atomicMax(&mkA[is1], 64 + lane);
  LDS_FENCE();

  // ---- P4: below via prefix-max; gather; new samples; rank scatter-add ----
  int m0 = mkA[lane], m1 = mkA[64 + lane];
  int bm0 = wscan_maxi(m0);
  int ball = readlaneNi<63>(bm0);
  int bm1 = imax2(wscan_maxi(m1), ball);

  float nzv[2], sgn[2];
  int rr_[2];
  #pragma unroll
  for (int s = 0; s < 2; ++s) {
    int i = lane + 64 * s;
    int below = s ? bm1 : bm0;             // max{k: cdf_k <= u_i}, in [0,125]
    float u = ((float)i + 0.5f) * (1.0f / UU);
    float2 pb0 = zcdf[below];              // (zc[b],   cdf[b])
    float2 pb1 = zcdf[below + 1];          // (zc[b+1], cdf[b+1])
    float pb2x = zcdf[below + 2].x;        // zc[b+2]
    float denom = pb1.y - pb0.y;
    if (denom < 1e-5f) denom = 1.0f;
    float t = (u - pb0.y) * frcp(denom);
    float bb = 0.5f * (pb0.x + pb1.x);
    float ba = 0.5f * (pb1.x + pb2x);
    float zn = __builtin_fmaf(t, ba - bb, bb);
    nzv[s] = zn;
    sgn[s] = interp_sigmaP(vP, zn, z0, invh);
    int rj = below + 1 + ((pb1.x <= zn) ? 1 : 0);  // rank of nz in zc, [1,127]
    rr_[s] = rj;
    atomicAdd(&mkB[rj], 1);
  }
  LDS_FENCE();

  // ---- P5: zc-rank via prefix-sum of rank histogram; scatter merged pairs ----
  int c0 = mkB[lane], c1 = mkB[64 + lane];
  int q0 = wscan_addi(c0);
  int qall = readlaneNi<63>(q0);
  int q1 = wscan_addi(c1) + qall;
  // zc_i -> pos i + #{j: r_j <= i}; nz_j -> pos j + r_j
  zg[lane + q0]           = make_float2(zloc[0], sgc0);
  zg[64 + lane + q1]      = make_float2(zloc[1], sgc1);
  zg[lane + rr_[0]]       = make_float2(nzv[0], sgn[0]);
  zg[64 + lane + rr_[1]]  = make_float2(nzv[1], sgn[1]);
  LDS_FENCE();

  // ---- P6: fine pass: sum sigma * delta over 256 merged samples ----
  float local = 0.0f;
  #pragma unroll
  for (int s = 0; s < 4; ++s) {
    int k = lane + 64 * s;
    int kp = (k < 2 * UU - 1) ? (k + 1) : (2 * UU - 1);
    float2 pk  = zg[k];
    float2 pk1 = zg[kp];
    float dlt = (k < 2 * UU - 1) ? (pk1.x - pk.x) : sd;
    local = __builtin_fmaf(pk.y, dlt, local);
  }
  float tsum = readlaneNf<63>(wscan_addf(local));
  if (active && lane == 0) out[ray] = fexp2(NLOG2E_F * tsum);
}

extern "C" void kernel_launch(void* const* d_in, const int* in_sizes, int n_in,
                              void* d_out, int out_size, void* d_ws, size_t ws_size,
                              hipStream_t stream) {
  const float* rays_o = (const float*)d_in[0];
  const float* rays_d = (const float*)d_in[1];
  const float* nearp  = (const float*)d_in[2];
  const float* farp   = (const float*)d_in[3];
  const float* noise  = (const float*)d_in[4];
  const float* W1     = (const float*)d_in[5];
  const float* b1     = (const float*)d_in[6];
  const float* W2     = (const float*)d_in[7];
  const float* b2     = (const float*)d_in[8];
  float* out = (float*)d_out;
  const int nrays = in_sizes[2];
  const int blocks = (nrays + WPB - 1) / WPB;
  nerf_transmittance_kernel<<<blocks, 256, 0, stream>>>(
      rays_o, rays_d, nearp, farp, noise, W1, b1, W2, b2, out, nrays);
}

// Round 11
// 23.806 us; speedup vs baseline: 13.0644x; 1.4165x over previous
//
#include <hip/hip_runtime.h>

#define UU 128          // coarse sample count per ray
#define HH 32           // hidden width
#define WPB 4           // waves per block
#define NN 32           // sigma interpolation nodes per ray (32-lane half-wave)

#define NLOG2E_F  (-1.44269504088896f)
#define TWOLOG2E_F  2.88539008177793f
#define LN2_F       0.693147180559945f
#define FLTMAX_I  0x7F7FFFFF   // bits of FLT_MAX (positive -> int-min == float-min)

__device__ __forceinline__ float fexp2(float x){ return __builtin_amdgcn_exp2f(x); }
__device__ __forceinline__ float flog2(float x){ return __builtin_amdgcn_logf(x); }
__device__ __forceinline__ float frcp (float x){ return __builtin_amdgcn_rcpf(x); }
template<int L>
__device__ __forceinline__ float readlaneNf(float x){
  return __int_as_float(__builtin_amdgcn_readlane(__float_as_int(x), L));
}

template<int CTRL, int RMASK>
__device__ __forceinline__ float dppmovf(float x){
  return __int_as_float(__builtin_amdgcn_update_dpp(
      0, __float_as_int(x), CTRL, RMASK, 0xF, true));
}
template<int CTRL, int RMASK>
__device__ __forceinline__ int dppmovi(int x){
  return __builtin_amdgcn_update_dpp(0, x, CTRL, RMASK, 0xF, true);
}
__device__ __forceinline__ int imax2(int a, int b){ return a > b ? a : b; }

// 32-lane SEGMENTED inclusive scans (two independent segments per wave):
// row_shr steps stay within 16-lane rows; bcast15 (row_mask 0xA -> rows 1,3)
// completes each 32-lane segment; omit bcast31 so segments stay independent.
__device__ __forceinline__ float seg32_scan_add(float v){
  v += dppmovf<0x111, 0xF>(v);
  v += dppmovf<0x112, 0xF>(v);
  v += dppmovf<0x114, 0xF>(v);
  v += dppmovf<0x118, 0xF>(v);
  v += dppmovf<0x142, 0xA>(v);
  return v;
}
__device__ __forceinline__ int seg32_scan_max(int v){
  v = imax2(v, dppmovi<0x111, 0xF>(v));
  v = imax2(v, dppmovi<0x112, 0xF>(v));
  v = imax2(v, dppmovi<0x114, 0xF>(v));
  v = imax2(v, dppmovi<0x118, 0xF>(v));
  v = imax2(v, dppmovi<0x142, 0xA>(v));
  return v;
}
// whole-wave shift right by 1 lane (crosses 16-lane rows); lane0 gets 0.
__device__ __forceinline__ int wave_shr1_i(int x){
  return __builtin_amdgcn_update_dpp(0, x, 0x138, 0xF, 0xF, true);
}

// all LDS arrays are wave-private: drain DS queue + stop compiler reordering.
#define LDS_FENCE() do { \
  asm volatile("s_waitcnt lgkmcnt(0)" ::: "memory"); \
  __builtin_amdgcn_wave_barrier(); \
} while (0)

// softplus(x) = max(x,0) + ln2*log2(1 + 2^(-log2e*|x|))
__device__ __forceinline__ float softplus_f(float x){
  float e = fexp2(NLOG2E_F * __builtin_fabsf(x));
  return __builtin_fmaxf(x, 0.0f) + LN2_F * flog2(1.0f + e);
}

// Catmull-Rom from overlapping-pair node table P[m] = (pad[m], pad[m+1]),
// pad = [n0, n0..n31, n31] (34 floats, 33 pairs). Cell i in [0, NN-2].
__device__ __forceinline__ float interp_sigmaP(const float2* P, float z,
                                               float z0, float invh){
  float t = __builtin_fmaxf((z - z0) * invh, 0.0f);
  int i = (int)t;
  i = (i < NN - 2) ? i : (NN - 2);
  float f = t - (float)i;
  float2 p01 = P[i];       // (pad[i],   pad[i+1])
  float2 p23 = P[i + 2];   // (pad[i+2], pad[i+3])
  float s0 = p01.x, s1 = p01.y, s2 = p23.x, s3 = p23.y;
  float a3 = __builtin_fmaf(1.5f, s1 - s2, 0.5f * (s3 - s0));
  float a2 = __builtin_fmaf(-2.5f, s1, s0) + __builtin_fmaf(-0.5f, s3, 2.0f * s2);
  float a1 = 0.5f * (s2 - s0);
  float p = __builtin_fmaf(__builtin_fmaf(__builtin_fmaf(a3, f, a2), f, a1), f, s1);
  return __builtin_fmaxf(p, 0.0f);
}

__global__ __launch_bounds__(256) void nerf_transmittance_kernel(
    const float* __restrict__ rays_o, const float* __restrict__ rays_d,
    const float* __restrict__ nearp, const float* __restrict__ farp,
    const float* __restrict__ noise, const float* __restrict__ W1,
    const float* __restrict__ b1, const float* __restrict__ W2,
    const float* __restrict__ b2, float* __restrict__ out, int nrays) {
  __shared__ __align__(16) float2 scg [WPB][2][HH];      // per-ray {c2,g2}
  __shared__ __align__(16) float2 sP  [WPB][2][NN + 2];  // node pair table
  __shared__ __align__(16) float2 szc [WPB][2][UU];      // (zc_k, cdf_k)
  __shared__ __align__(16) int    smkA[WPB][2][UU];      // scatter-max slots
  __shared__ __align__(16) int    sfnz[WPB][2][UU];      // firstnz (float bits)

  const int tid  = threadIdx.x;
  const int wave = tid >> 6;
  const int lane = tid & 63;
  const int half = lane >> 5;          // which ray of the pair
  const int li   = lane & 31;          // lane within the 32-lane segment
  const int base = (blockIdx.x * WPB + wave) * 2;   // wave-uniform
  const int rA = (base < nrays) ? base : (nrays - 1);
  const int rB = (base + 1 < nrays) ? (base + 1) : (nrays - 1);
  const bool isB = (half != 0);

  // uniform scalar loads for both rays, per-lane select
  const float ox = isB ? rays_o[3*rB+0] : rays_o[3*rA+0];
  const float oy = isB ? rays_o[3*rB+1] : rays_o[3*rA+1];
  const float oz = isB ? rays_o[3*rB+2] : rays_o[3*rA+2];
  const float dx = isB ? rays_d[3*rB+0] : rays_d[3*rA+0];
  const float dy = isB ? rays_d[3*rB+1] : rays_d[3*rA+1];
  const float dz = isB ? rays_d[3*rB+2] : rays_d[3*rA+2];
  const float nv = isB ? nearp[rB] : nearp[rA];
  const float fv = isB ? farp[rB]  : farp[rA];
  const float sd   = (fv - nv) * (1.0f / UU);
  const float step = (fv - nv) * (1.0f / (UU - 1));

  // W2/b2 uniform: bacc = b2 + sum(w2); n2w2 = -2*w2 (SGPRs)
  float n2w2[HH];
  float bacc = b2[0];
  #pragma unroll
  for (int j = 0; j < HH; ++j) {
    float w2 = W2[j];
    bacc += w2;
    n2w2[j] = -2.0f * w2;
  }

  float2* cgh = &scg[wave][half][0];
  float2* vPh = &sP [wave][half][0];
  float2* zct = &szc[wave][half][0];
  int*    mka = &smkA[wave][half][0];
  int*    fnz = &sfnz[wave][half][0];

  // ---- P1: zero scatter arrays; per-ray affine fold (unit j = li) ----
  *(int4*)&mka[4*li] = make_int4(0, 0, 0, 0);
  *(int4*)&fnz[4*li] = make_int4(FLTMAX_I, FLTMAX_I, FLTMAX_I, FLTMAX_I);
  {
    float wx = W1[li], wy = W1[HH + li], wz = W1[2*HH + li];
    float g = dx*wx + dy*wy + dz*wz;
    float c = ox*wx + oy*wy + oz*wz + b1[li];
    cgh[li] = make_float2(TWOLOG2E_F * c, TWOLOG2E_F * g);
  }
  LDS_FENCE();

  // ---- P2: node MLP — each lane evaluates node li of its ray ----
  const float z0   = nv - 0.5f * sd;
  const float span = (fv - nv) + sd;
  const float h    = span * (1.0f / (NN - 1));
  const float invh = (float)(NN - 1) * frcp(span);
  {
    float zn = __builtin_fmaf((float)li, h, z0);
    float acc = bacc;
    #pragma unroll
    for (int j = 0; j < HH; ++j) {
      const float2 c = cgh[j];                // 2-addr broadcast (free)
      float q = __builtin_fmaf(c.y, zn, c.x); // 2log2e * pre
      float e = fexp2(q);
      float rr = frcp(1.0f + e);              // tanh = 1 - 2r
      acc = __builtin_fmaf(n2w2[j], rr, acc);
    }
    float v = softplus_f(acc);
    ((float*)&vPh[li + 1])[0] = v;            // pad[li+1] = v
    ((float*)&vPh[li])[1]     = v;
    if (li == 0)      ((float*)&vPh[0])[0]  = v;   // pad[0]
    if (li == NN - 1) ((float*)&vPh[NN])[1] = v;   // pad[NN+1]
  }
  LDS_FENCE();

  // ---- P3: coarse z/sigma, segmented scan, telescoped cdf, i* scatter ----
  const int rcur = isB ? rB : rA;
  const size_t nb = (size_t)rcur * UU;
  float4 n4 = *(const float4*)&noise[nb + 4*li];
  int nxi = 4*li + 4; nxi = (nxi < UU - 1) ? nxi : (UU - 1);
  float n5 = noise[nb + nxi];
  float nn_[5] = {n4.x, n4.y, n4.z, n4.w, n5};

  float zl[4], dl[4], sig[4];
  #pragma unroll
  for (int c = 0; c < 4; ++c) {
    zl[c] = __builtin_fmaf(step, (float)(4*li + c), nv) + (nn_[c] - 0.5f) * sd;
    dl[c] = step + (nn_[c+1] - nn_[c]) * sd;
    sig[c] = interp_sigmaP(vPh, zl[c], z0, invh);
  }
  if (li == 31) dl[3] = sd;   // sample 127's delta

  float a0 = dl[0]*sig[0], a1 = dl[1]*sig[1], a2 = dl[2]*sig[2], a3 = dl[3]*sig[3];
  float t0 = a0, t1 = t0 + a1, t2 = t1 + a2, t3 = t2 + a3;
  float incl = seg32_scan_add(t3);
  float excl = incl - t3;
  float Ti[4];
  Ti[0] = fexp2(NLOG2E_F * (excl + t0));
  Ti[1] = fexp2(NLOG2E_F * (excl + t1));
  Ti[2] = fexp2(NLOG2E_F * (excl + t2));
  Ti[3] = fexp2(NLOG2E_F * (excl + t3));

  float T1x  = isB ? readlaneNf<32>(Ti[0]) : readlaneNf<0>(Ti[0]);   // Tincl(0)
  float T126 = isB ? readlaneNf<63>(Ti[2]) : readlaneNf<31>(Ti[2]);  // Tincl(126)
  float itot = frcp(T1x - T126 + 126.0f * 1e-5f);

  float cdfv[4];
  #pragma unroll
  for (int c = 0; c < 4; ++c)
    cdfv[c] = (T1x - Ti[c] + (float)(4*li + c) * 1e-5f) * itot;

  *(float4*)&zct[4*li]     = make_float4(zl[0], cdfv[0], zl[1], cdfv[1]);
  *(float4*)&zct[4*li + 2] = make_float4(zl[2], cdfv[2], zl[3], cdfv[3]);

  #pragma unroll
  for (int c = 0; c < 4; ++c) {
    int k = 4*li + c;
    int is = (int)__builtin_ceilf(__builtin_fmaf(cdfv[c], 128.0f, -0.5f));
    if (k < 127 && is < 128) atomicMax(&mka[is], k);
  }
  LDS_FENCE();

  // ---- P4: below via segmented prefix-max; sample; rank; firstnz scatter ----
  int4 m4 = *(int4*)&mka[4*li];
  int M3 = imax2(imax2(m4.x, m4.y), imax2(m4.z, m4.w));
  int incm = seg32_scan_max(M3);
  int exm = wave_shr1_i(incm);
  exm = (li == 0) ? 0 : exm;
  int bcv[4];
  bcv[0] = imax2(exm, m4.x);
  bcv[1] = imax2(bcv[0], m4.y);
  bcv[2] = imax2(bcv[1], m4.z);
  bcv[3] = imax2(bcv[2], m4.w);

  float nzv[4], sgn2[4];
  int rj[4];
  #pragma unroll
  for (int c = 0; c < 4; ++c) {
    float u = ((float)(4*li + c) + 0.5f) * (1.0f / UU);
    int b = bcv[c];                       // max{k: cdf_k <= u}, in [0,125]
    float2 p0 = zct[b];
    float2 p1 = zct[b + 1];
    float p2x = zct[b + 2].x;
    float den = p1.y - p0.y;
    if (den < 1e-5f) den = 1.0f;
    float t = (u - p0.y) * frcp(den);
    float bb = 0.5f * (p0.x + p1.x);
    float ba = 0.5f * (p1.x + p2x);
    float z = __builtin_fmaf(t, ba - bb, bb);
    nzv[c] = z;
    sgn2[c] = interp_sigmaP(vPh, z, z0, invh);
    rj[c] = b + 1 + ((p1.x <= z) ? 1 : 0);     // rank of nz in zc, [1,127]
    atomicMin(&fnz[rj[c]], __float_as_int(z)); // positive floats: int min ok
  }
  LDS_FENCE();

  // ---- P5: analytic merged-successor deltas, fused transmittance sum ----
  // succ(zc_i) = min(zc_{i+1}, firstnz[i+1]);  succ(nz_j) = min(nz_{j+1}, zc[r_j])
  int4 f4 = *(int4*)&fnz[4*li];
  float nzn3 = __shfl_down(nzv[0], 1);                 // nz_{j+1} for c=3
  float zcn3 = __shfl_down(zl[0], 1);                  // zc_{i+1} for c=3
  int   fnn3 = __shfl_down(f4.x, 1);                   // firstnz[i+1] for c=3
  const bool lastl = (li == 31);

  float local = 0.0f;
  // zc side
  local += sig[0] * (__builtin_fminf(zl[1], __int_as_float(f4.y)) - zl[0]);
  local += sig[1] * (__builtin_fminf(zl[2], __int_as_float(f4.z)) - zl[1]);
  local += sig[2] * (__builtin_fminf(zl[3], __int_as_float(f4.w)) - zl[2]);
  float succ3 = lastl ? (zl[3] + sd)
                      : __builtin_fminf(zcn3, __int_as_float(fnn3));
  local += sig[3] * (succ3 - zl[3]);
  // nz side
  float zr0 = zct[rj[0]].x, zr1 = zct[rj[1]].x, zr2 = zct[rj[2]].x, zr3 = zct[rj[3]].x;
  local += sgn2[0] * (__builtin_fminf(nzv[1], zr0) - nzv[0]);
  local += sgn2[1] * (__builtin_fminf(nzv[2], zr1) - nzv[1]);
  local += sgn2[2] * (__builtin_fminf(nzv[3], zr2) - nzv[2]);
  float nzn = lastl ? __int_as_float(FLTMAX_I) : nzn3;
  local += sgn2[3] * (__builtin_fminf(nzn, zr3) - nzv[3]);

  float tot = seg32_scan_add(local);    // lane 31/63 holds each ray's total
  if (li == 31) {
    int ray = base + half;
    if (ray < nrays) out[ray] = fexp2(NLOG2E_F * tot);
  }
}

extern "C" void kernel_launch(void* const* d_in, const int* in_sizes, int n_in,
                              void* d_out, int out_size, void* d_ws, size_t ws_size,
                              hipStream_t stream) {
  const float* rays_o = (const float*)d_in[0];
  const float* rays_d = (const float*)d_in[1];
  const float* nearp  = (const float*)d_in[2];
  const float* farp   = (const float*)d_in[3];
  const float* noise  = (const float*)d_in[4];
  const float* W1     = (const float*)d_in[5];
  const float* b1     = (const float*)d_in[6];
  const float* W2     = (const float*)d_in[7];
  const float* b2     = (const float*)d_in[8];
  float* out = (float*)d_out;
  const int nrays = in_sizes[2];
  const int raysPerBlock = WPB * 2;
  const int blocks = (nrays + raysPerBlock - 1) / raysPerBlock;
  nerf_transmittance_kernel<<<blocks, 256, 0, stream>>>(
      rays_o, rays_d, nearp, farp, noise, W1, b1, W2, b2, out, nrays);
}

// Round 12
// 22.631 us; speedup vs baseline: 13.7428x; 1.0519x over previous
//
#include <hip/hip_runtime.h>

#define UU 128          // coarse sample count per ray
#define HH 32           // hidden width
#define WPB 4           // waves per block
#define NN 32           // sigma interpolation nodes per ray (32-lane half-wave)

#define NLOG2E_F  (-1.44269504088896f)
#define TWOLOG2E_F  2.88539008177793f
#define LN2_F       0.693147180559945f
#define FLTMAX_I  0x7F7FFFFF   // bits of FLT_MAX (positive -> int-min == float-min)

__device__ __forceinline__ float fexp2(float x){ return __builtin_amdgcn_exp2f(x); }
__device__ __forceinline__ float flog2(float x){ return __builtin_amdgcn_logf(x); }
__device__ __forceinline__ float frcp (float x){ return __builtin_amdgcn_rcpf(x); }
template<int L>
__device__ __forceinline__ float readlaneNf(float x){
  return __int_as_float(__builtin_amdgcn_readlane(__float_as_int(x), L));
}

template<int CTRL, int RMASK>
__device__ __forceinline__ float dppmovf(float x){
  return __int_as_float(__builtin_amdgcn_update_dpp(
      0, __float_as_int(x), CTRL, RMASK, 0xF, true));
}
template<int CTRL, int RMASK>
__device__ __forceinline__ int dppmovi(int x){
  return __builtin_amdgcn_update_dpp(0, x, CTRL, RMASK, 0xF, true);
}
__device__ __forceinline__ int imax2(int a, int b){ return a > b ? a : b; }

// 32-lane SEGMENTED inclusive scans (two independent segments per wave)
__device__ __forceinline__ float seg32_scan_add(float v){
  v += dppmovf<0x111, 0xF>(v);
  v += dppmovf<0x112, 0xF>(v);
  v += dppmovf<0x114, 0xF>(v);
  v += dppmovf<0x118, 0xF>(v);
  v += dppmovf<0x142, 0xA>(v);
  return v;
}
__device__ __forceinline__ int seg32_scan_max(int v){
  v = imax2(v, dppmovi<0x111, 0xF>(v));
  v = imax2(v, dppmovi<0x112, 0xF>(v));
  v = imax2(v, dppmovi<0x114, 0xF>(v));
  v = imax2(v, dppmovi<0x118, 0xF>(v));
  v = imax2(v, dppmovi<0x142, 0xA>(v));
  return v;
}
// whole-wave shift right by 1 lane; lane0 gets 0.
__device__ __forceinline__ int wave_shr1_i(int x){
  return __builtin_amdgcn_update_dpp(0, x, 0x138, 0xF, 0xF, true);
}

// Soft fence: same-wave DS ops execute in order on the LDS pipe, so
// write->read visibility within a wave needs only a compiler barrier
// (no lgkmcnt(0) drain). wave_barrier pins scheduling.
#define LDS_SOFT() do { \
  asm volatile("" ::: "memory"); \
  __builtin_amdgcn_wave_barrier(); \
} while (0)

// softplus(x) = max(x,0) + ln2*log2(1 + 2^(-log2e*|x|))
__device__ __forceinline__ float softplus_f(float x){
  float e = fexp2(NLOG2E_F * __builtin_fabsf(x));
  return __builtin_fmaxf(x, 0.0f) + LN2_F * flog2(1.0f + e);
}

// Catmull-Rom via precomputed per-cell coefficients C[i] = (s1, a1, a2, a3):
// sigma(z) = ((a3*f + a2)*f + a1)*f + s1,  f = frac within cell i.
__device__ __forceinline__ float interp_sigmaC(const float4* C, float z,
                                               float z0, float invh){
  float t = __builtin_fmaxf((z - z0) * invh, 0.0f);
  int i = (int)t;
  i = (i < NN - 2) ? i : (NN - 2);
  float f = t - (float)i;
  float4 c = C[i];
  float p = __builtin_fmaf(__builtin_fmaf(__builtin_fmaf(c.w, f, c.z), f, c.y), f, c.x);
  return __builtin_fmaxf(p, 0.0f);
}

__global__ __launch_bounds__(256) void nerf_transmittance_kernel(
    const float* __restrict__ rays_o, const float* __restrict__ rays_d,
    const float* __restrict__ nearp, const float* __restrict__ farp,
    const float* __restrict__ noise, const float* __restrict__ W1,
    const float* __restrict__ b1, const float* __restrict__ W2,
    const float* __restrict__ b2, float* __restrict__ out, int nrays) {
  __shared__ __align__(16) float2 scg [WPB][2][HH];      // per-ray {c2,g2}
  __shared__ __align__(16) float4 scf [WPB][2][NN];      // cell coeffs [0..30]
  __shared__ __align__(16) float2 szc [WPB][2][UU];      // (zc_k, cdf_k)
  __shared__ __align__(16) int    smkA[WPB][2][UU];      // scatter-max slots
  __shared__ __align__(16) int    sfnz[WPB][2][UU];      // firstnz (float bits)

  const int tid  = threadIdx.x;
  const int wave = tid >> 6;
  const int lane = tid & 63;
  const int half = lane >> 5;          // which ray of the pair
  const int li   = lane & 31;          // lane within the 32-lane segment
  const int base = (blockIdx.x * WPB + wave) * 2;   // wave-uniform
  const int rA = (base < nrays) ? base : (nrays - 1);
  const int rB = (base + 1 < nrays) ? (base + 1) : (nrays - 1);
  const bool isB = (half != 0);

  // uniform scalar loads for both rays, per-lane select
  const float ox = isB ? rays_o[3*rB+0] : rays_o[3*rA+0];
  const float oy = isB ? rays_o[3*rB+1] : rays_o[3*rA+1];
  const float oz = isB ? rays_o[3*rB+2] : rays_o[3*rA+2];
  const float dx = isB ? rays_d[3*rB+0] : rays_d[3*rA+0];
  const float dy = isB ? rays_d[3*rB+1] : rays_d[3*rA+1];
  const float dz = isB ? rays_d[3*rB+2] : rays_d[3*rA+2];
  const float nv = isB ? nearp[rB] : nearp[rA];
  const float fv = isB ? farp[rB]  : farp[rA];
  const float sd   = (fv - nv) * (1.0f / UU);
  const float step = (fv - nv) * (1.0f / (UU - 1));

  // W2/b2 uniform: bacc = b2 + sum(w2); n2w2 = -2*w2 (SGPRs)
  float n2w2[HH];
  float bacc = b2[0];
  #pragma unroll
  for (int j = 0; j < HH; ++j) {
    float w2 = W2[j];
    bacc += w2;
    n2w2[j] = -2.0f * w2;
  }

  float2* cgh = &scg[wave][half][0];
  float4* cfh = &scf[wave][half][0];
  float2* zct = &szc[wave][half][0];
  int*    mka = &smkA[wave][half][0];
  int*    fnz = &sfnz[wave][half][0];

  // ---- P1: zero scatter arrays; per-ray affine fold (unit j = li) ----
  *(int4*)&mka[4*li] = make_int4(0, 0, 0, 0);
  *(int4*)&fnz[4*li] = make_int4(FLTMAX_I, FLTMAX_I, FLTMAX_I, FLTMAX_I);
  {
    float wx = W1[li], wy = W1[HH + li], wz = W1[2*HH + li];
    float g = dx*wx + dy*wy + dz*wz;
    float c = ox*wx + oy*wy + oz*wz + b1[li];
    cgh[li] = make_float2(TWOLOG2E_F * c, TWOLOG2E_F * g);
  }
  LDS_SOFT();

  // ---- P2: node MLP (lane li -> node li); build cell coeff table ----
  const float z0   = nv - 0.5f * sd;
  const float span = (fv - nv) + sd;
  const float invh = (float)(NN - 1) * frcp(span);
  const float h    = span * (1.0f / (NN - 1));
  {
    float zn = __builtin_fmaf((float)li, h, z0);
    float acc = bacc;
    #pragma unroll
    for (int j = 0; j < HH; ++j) {
      const float2 c = cgh[j];                // 2-addr broadcast read
      float q = __builtin_fmaf(c.y, zn, c.x); // 2log2e * pre
      float e = fexp2(q);
      float rr = frcp(1.0f + e);              // tanh = 1 - 2r
      acc = __builtin_fmaf(n2w2[j], rr, acc);
    }
    float v = softplus_f(acc);

    // neighbor exchange within the 32-lane segment (edge-clamped)
    int lm1 = (li > 0)  ? (lane - 1) : lane;
    int lp1 = (li < 31) ? (lane + 1) : lane;
    int lp2 = (li < 30) ? (lane + 2) : (31 + 32 * half);
    float s0 = __shfl(v, lm1, 64);   // v_{i-1} (i=0 -> v_0)
    float s2 = __shfl(v, lp1, 64);   // v_{i+1}
    float s3 = __shfl(v, lp2, 64);   // v_{i+2} (i=30 -> v_31)
    // cell i coeffs: s1=v_i
    if (li < NN - 1) {
      float a1 = 0.5f * (s2 - s0);
      float a3 = __builtin_fmaf(1.5f, v - s2, 0.5f * (s3 - s0));
      float a2 = __builtin_fmaf(-2.5f, v, s0) + __builtin_fmaf(-0.5f, s3, 2.0f * s2);
      cfh[li] = make_float4(v, a1, a2, a3);
    }
  }
  LDS_SOFT();

  // ---- P3: coarse z/sigma, segmented scan, telescoped cdf, i* scatter ----
  const int rcur = isB ? rB : rA;
  const size_t nb = (size_t)rcur * UU;
  float4 n4 = *(const float4*)&noise[nb + 4*li];
  int nxi = 4*li + 4; nxi = (nxi < UU - 1) ? nxi : (UU - 1);
  float n5 = noise[nb + nxi];
  float nn_[5] = {n4.x, n4.y, n4.z, n4.w, n5};

  float zl[4], dl[4], sig[4];
  #pragma unroll
  for (int c = 0; c < 4; ++c) {
    zl[c] = __builtin_fmaf(step, (float)(4*li + c), nv) + (nn_[c] - 0.5f) * sd;
    dl[c] = step + (nn_[c+1] - nn_[c]) * sd;
    sig[c] = interp_sigmaC(cfh, zl[c], z0, invh);
  }
  if (li == 31) dl[3] = sd;   // sample 127's delta

  float a0 = dl[0]*sig[0], a1 = dl[1]*sig[1], a2 = dl[2]*sig[2], a3 = dl[3]*sig[3];
  float t0 = a0, t1 = t0 + a1, t2 = t1 + a2, t3 = t2 + a3;
  float incl = seg32_scan_add(t3);
  float excl = incl - t3;
  float Ti[4];
  Ti[0] = fexp2(NLOG2E_F * (excl + t0));
  Ti[1] = fexp2(NLOG2E_F * (excl + t1));
  Ti[2] = fexp2(NLOG2E_F * (excl + t2));
  Ti[3] = fexp2(NLOG2E_F * (excl + t3));

  float T1x  = isB ? readlaneNf<32>(Ti[0]) : readlaneNf<0>(Ti[0]);   // Tincl(0)
  float T126 = isB ? readlaneNf<63>(Ti[2]) : readlaneNf<31>(Ti[2]);  // Tincl(126)
  float itot = frcp(T1x - T126 + 126.0f * 1e-5f);

  float cdfv[4];
  #pragma unroll
  for (int c = 0; c < 4; ++c)
    cdfv[c] = (T1x - Ti[c] + (float)(4*li + c) * 1e-5f) * itot;

  *(float4*)&zct[4*li]     = make_float4(zl[0], cdfv[0], zl[1], cdfv[1]);
  *(float4*)&zct[4*li + 2] = make_float4(zl[2], cdfv[2], zl[3], cdfv[3]);

  #pragma unroll
  for (int c = 0; c < 4; ++c) {
    int k = 4*li + c;
    int is = (int)__builtin_ceilf(__builtin_fmaf(cdfv[c], 128.0f, -0.5f));
    if (k < 127 && is < 128) atomicMax(&mka[is], k);
  }
  LDS_SOFT();

  // ---- P4: below via segmented prefix-max; sample; rank; firstnz scatter ----
  int4 m4 = *(int4*)&mka[4*li];
  int M3 = imax2(imax2(m4.x, m4.y), imax2(m4.z, m4.w));
  int incm = seg32_scan_max(M3);
  int exm = wave_shr1_i(incm);
  exm = (li == 0) ? 0 : exm;
  int bcv[4];
  bcv[0] = imax2(exm, m4.x);
  bcv[1] = imax2(bcv[0], m4.y);
  bcv[2] = imax2(bcv[1], m4.z);
  bcv[3] = imax2(bcv[2], m4.w);

  float nzv[4], sgn2[4], zrv[4];
  #pragma unroll
  for (int c = 0; c < 4; ++c) {
    float u = ((float)(4*li + c) + 0.5f) * (1.0f / UU);
    int b = bcv[c];                       // max{k: cdf_k <= u}, in [0,125]
    float2 p0 = zct[b];
    float2 p1 = zct[b + 1];
    float p2x = zct[b + 2].x;
    float den = p1.y - p0.y;
    if (den < 1e-5f) den = 1.0f;
    float t = (u - p0.y) * frcp(den);
    float bb = 0.5f * (p0.x + p1.x);
    float ba = 0.5f * (p1.x + p2x);
    float z = __builtin_fmaf(t, ba - bb, bb);
    nzv[c] = z;
    sgn2[c] = interp_sigmaC(cfh, z, z0, invh);
    bool up = (p1.x <= z);
    int rj = b + 1 + (up ? 1 : 0);             // rank of nz in zc, [1,127]
    zrv[c] = up ? p2x : p1.x;                  // zc[rank] from registers
    atomicMin(&fnz[rj], __float_as_int(z));    // positive floats: int min ok
  }
  LDS_SOFT();

  // ---- P5: analytic merged-successor deltas, fused transmittance sum ----
  // succ(zc_i) = min(zc_{i+1}, firstnz[i+1]);  succ(nz_j) = min(nz_{j+1}, zc[r_j])
  int4 f4 = *(int4*)&fnz[4*li];
  float nzn3 = __shfl_down(nzv[0], 1);                 // nz_{j+1} for c=3
  float zcn3 = __shfl_down(zl[0], 1);                  // zc_{i+1} for c=3
  int   fnn3 = __shfl_down(f4.x, 1);                   // firstnz[i+1] for c=3
  const bool lastl = (li == 31);

  float local = 0.0f;
  // zc side
  local += sig[0] * (__builtin_fminf(zl[1], __int_as_float(f4.y)) - zl[0]);
  local += sig[1] * (__builtin_fminf(zl[2], __int_as_float(f4.z)) - zl[1]);
  local += sig[2] * (__builtin_fminf(zl[3], __int_as_float(f4.w)) - zl[2]);
  float succ3 = lastl ? (zl[3] + sd)
                      : __builtin_fminf(zcn3, __int_as_float(fnn3));
  local += sig[3] * (succ3 - zl[3]);
  // nz side
  local += sgn2[0] * (__builtin_fminf(nzv[1], zrv[0]) - nzv[0]);
  local += sgn2[1] * (__builtin_fminf(nzv[2], zrv[1]) - nzv[1]);
  local += sgn2[2] * (__builtin_fminf(nzv[3], zrv[2]) - nzv[2]);
  float nzn = lastl ? __int_as_float(FLTMAX_I) : nzn3;
  local += sgn2[3] * (__builtin_fminf(nzn, zrv[3]) - nzv[3]);

  float tot = seg32_scan_add(local);    // lane 31/63 holds each ray's total
  if (li == 31) {
    int ray = base + half;
    if (ray < nrays) out[ray] = fexp2(NLOG2E_F * tot);
  }
}

extern "C" void kernel_launch(void* const* d_in, const int* in_sizes, int n_in,
                              void* d_out, int out_size, void* d_ws, size_t ws_size,
                              hipStream_t stream) {
  const float* rays_o = (const float*)d_in[0];
  const float* rays_d = (const float*)d_in[1];
  const float* nearp  = (const float*)d_in[2];
  const float* farp   = (const float*)d_in[3];
  const float* noise  = (const float*)d_in[4];
  const float* W1     = (const float*)d_in[5];
  const float* b1     = (const float*)d_in[6];
  const float* W2     = (const float*)d_in[7];
  const float* b2     = (const float*)d_in[8];
  float* out = (float*)d_out;
  const int nrays = in_sizes[2];
  const int raysPerBlock = WPB * 2;
  const int blocks = (nrays + raysPerBlock - 1) / raysPerBlock;
  nerf_transmittance_kernel<<<blocks, 256, 0, stream>>>(
      rays_o, rays_d, nearp, farp, noise, W1, b1, W2, b2, out, nrays);
}